// Round 15
// baseline (594.583 us; speedup 1.0000x reference)
//
#include <hip/hip_runtime.h>
#include <hip/hip_bf16.h>
#include <math.h>

#define B_ 8
#define T_ 2048
#define PT_ 2112   // T_ + 64 zero-pad rows at the start of each batch
#define DIN_ 64
#define D_ 512

typedef __attribute__((ext_vector_type(8))) short bf16x8;
typedef __attribute__((ext_vector_type(4))) float f32x4;

#define HROW(b, t) (((size_t)(b) * PT_ + 64 + (t)) * D_)

__device__ __forceinline__ float gelu_f(float x) {
    return 0.5f * x * (1.0f + erff(x * 0.70710678118654752440f));
}
__device__ __forceinline__ float bfu2f(unsigned short u) {
    union { float f; unsigned int i; } v; v.i = ((unsigned int)u) << 16; return v.f;
}
__device__ __forceinline__ unsigned short f2bf(float f) {
    unsigned int x = __float_as_uint(f);
    return (unsigned short)((x + 0x7FFFu + ((x >> 16) & 1u)) >> 16);
}
// async global->LDS, 16B per lane; lds dest is wave-uniform base (+ lane*16 by HW)
__device__ __forceinline__ void gload_lds16(const void* g, void* l) {
    __builtin_amdgcn_global_load_lds(
        (const __attribute__((address_space(1))) void*)g,
        (__attribute__((address_space(3))) void*)l, 16, 0, 0);
}

// -------- fused setup: zero pad rows + fp32->bf16 input convert + zero zvb --------
__global__ __launch_bounds__(256) void k_setup(const float* __restrict__ x,
                                               unsigned short* __restrict__ xb,
                                               unsigned short* bufA,
                                               unsigned short* bufB,
                                               float* zvb) {
    const int NX = B_ * 64 * DIN_;            // xb pad
    const int NA = B_ * 64 * D_;              // bufA/bufB pad each
    const int NC = B_ * T_ * DIN_;            // x convert
    const int NZ = B_ * D_;                   // zvb zero
    int i = blockIdx.x * 256 + threadIdx.x;
    if (i < NX) {
        const int b = i / (64 * DIN_), r = i - b * (64 * DIN_);
        xb[(size_t)b * PT_ * DIN_ + r] = 0;
        return;
    }
    i -= NX;
    if (i < NA) {
        const int b = i / (64 * D_), r = i - b * (64 * D_);
        bufA[(size_t)b * PT_ * D_ + r] = 0;
        return;
    }
    i -= NA;
    if (i < NA) {
        const int b = i / (64 * D_), r = i - b * (64 * D_);
        bufB[(size_t)b * PT_ * D_ + r] = 0;
        return;
    }
    i -= NA;
    if (i < NC) {
        const int b = i / (T_ * DIN_);
        const int r = i - b * (T_ * DIN_);
        xb[((size_t)b * PT_ + 64) * DIN_ + r] = f2bf(x[i]);
        return;
    }
    i -= NC;
    if (i < NZ) zvb[i] = 0.0f;
}

// -------- fused weight convert+transpose for ALL 13 conv weight tensors --------
__global__ __launch_bounds__(256) void k_wcvt_all(const float* resw, const float* c1w0,
                                                  const float* c2w0, const float* c1w,
                                                  const float* c2w,
                                                  unsigned short* wRes, unsigned short* wC10,
                                                  unsigned short* wC20, unsigned short* wC1,
                                                  unsigned short* wC2) {
    const int l = blockIdx.y;
    const float* src;
    unsigned short* dst;
    int C_in, KS;
    if (l == 0)      { src = resw; dst = wRes; C_in = 64;  KS = 1; }
    else if (l == 1) { src = c1w0; dst = wC10; C_in = 64;  KS = 3; }
    else if (l == 2) { src = c2w0; dst = wC20; C_in = 512; KS = 3; }
    else if (l <= 7) { src = c1w + (size_t)(l - 3) * 512 * 512 * 3;
                       dst = wC1 + (size_t)(l - 3) * 3 * 512 * 512; C_in = 512; KS = 3; }
    else             { src = c2w + (size_t)(l - 8) * 512 * 512 * 3;
                       dst = wC2 + (size_t)(l - 8) * 3 * 512 * 512; C_in = 512; KS = 3; }
    const int n = 512 * C_in * KS;
    for (int i = blockIdx.x * 256 + threadIdx.x; i < n; i += gridDim.x * 256) {
        const int ci = i % C_in;
        const int r = i / C_in;
        const int co = r & 511;
        const int tap = r >> 9;
        dst[i] = f2bf(src[((size_t)co * C_in + ci) * KS + tap]);
    }
}

// -------- block-0 dual conv: y=0 -> 1x1 residual->bufA; y=1 -> 3-tap gelu->bufB --------
// Both C_in=64 (single chunk), dil=1. Independent -> co-run in one dispatch.
__global__ __launch_bounds__(256, 2) void k_conv_b0(const unsigned short* __restrict__ X,
                                                    const unsigned short* __restrict__ wRes,
                                                    const float* __restrict__ resb,
                                                    const unsigned short* __restrict__ wC10,
                                                    const float* __restrict__ c1b0,
                                                    unsigned short* bufA,
                                                    unsigned short* bufB) {
    const int tid = threadIdx.x;
    const int ib = blockIdx.x;
    const int work = (ib & 7) * 8 + (ib >> 3);
    const int co0 = (work & 3) * 128;
    const int t0 = (work >> 2) * 128;
    const int b = blockIdx.z;
    const int y = blockIdx.y;
    const int nks = y ? 3 : 1;
    const unsigned short* Wt = y ? wC10 : wRes;
    const float* bias = y ? c1b0 : resb;
    unsigned short* Y = y ? bufB : bufA;
    const int back = nks - 1;            // dil=1
    const int nx = (128 + back) * 8;

    __shared__ __align__(16) unsigned short sX[192 * 64];
    __shared__ __align__(16) unsigned short sW[3 * 128 * 64];

    const int lane = tid & 63;
    const int wv = tid >> 6;
    const int wco = (wv & 1) * 64;
    const int wt = (wv >> 1) * 64;
    const int tl = lane & 15;
    const int ch = lane >> 4;

    f32x4 acc[4][4] = {};

    const unsigned short* Xb = X + ((size_t)b * PT_ + 64) * DIN_;

#pragma unroll
    for (int k = 0; k < 6; ++k) {
        const int i = tid + k * 256;
        if (i < nx) {
            const int row = i >> 3, s = i & 7;
            int tg = t0 - back + row;
            if (tg >= T_) tg = T_ - 1;
            gload_lds16(Xb + (size_t)tg * DIN_ + ((s ^ (row & 7)) << 3), &sX[(i & ~63) * 8]);
        }
    }
    for (int k = 0; k < nks * 4; ++k) {
        const int i = tid + k * 256;
        const int row = i >> 3, s = i & 7;
        const int tap = row >> 7, rco = row & 127;
        gload_lds16(Wt + ((size_t)(tap * 512 + co0 + rco)) * DIN_ + ((s ^ (row & 7)) << 3),
                    &sW[(i & ~63) * 8]);
    }
    __syncthreads();

    for (int tap = 0; tap < nks; ++tap) {
        const int tapoff = tap;
#pragma unroll
        for (int kh = 0; kh < 2; ++kh) {
            const int j = kh * 4 + ch;
            bf16x8 a[4], bb[4];
#pragma unroll
            for (int m = 0; m < 4; ++m) {
                const int wr = tap * 128 + wco + m * 16 + tl;
                a[m] = *reinterpret_cast<const bf16x8*>(&sW[wr * 64 + ((j ^ (wr & 7)) << 3)]);
            }
#pragma unroll
            for (int n = 0; n < 4; ++n) {
                const int xr = wt + n * 16 + tl + tapoff;
                bb[n] = *reinterpret_cast<const bf16x8*>(&sX[xr * 64 + ((j ^ (xr & 7)) << 3)]);
            }
#pragma unroll
            for (int m = 0; m < 4; ++m)
#pragma unroll
                for (int n = 0; n < 4; ++n)
                    acc[m][n] = __builtin_amdgcn_mfma_f32_16x16x32_bf16(a[m], bb[n], acc[m][n], 0, 0, 0);
        }
    }

#pragma unroll
    for (int m = 0; m < 4; ++m) {
        const int co = co0 + wco + m * 16 + ch * 4;
        const float4 bv4 = *reinterpret_cast<const float4*>(&bias[co]);
#pragma unroll
        for (int n = 0; n < 4; ++n) {
            const int t = t0 + wt + n * 16 + tl;
            const size_t base = HROW(b, t) + co;
            float v[4];
            v[0] = acc[m][n][0] + bv4.x;
            v[1] = acc[m][n][1] + bv4.y;
            v[2] = acc[m][n][2] + bv4.z;
            v[3] = acc[m][n][3] + bv4.w;
            if (y) {
#pragma unroll
                for (int r = 0; r < 4; ++r) v[r] = gelu_f(v[r]);
            }
            uint2 o;
            o.x = (unsigned int)f2bf(v[0]) | ((unsigned int)f2bf(v[1]) << 16);
            o.y = (unsigned int)f2bf(v[2]) | ((unsigned int)f2bf(v[3]) << 16);
            *reinterpret_cast<uint2*>(&Y[base]) = o;
        }
    }
}

// -------- causal dilated conv via bf16 MFMA implicit GEMM (R11, measured best) --------
template <int KS, int MODE>
__global__ __launch_bounds__(256, 2) void k_conv_mfma(const unsigned short* __restrict__ X,
                                                      const unsigned short* __restrict__ Wt,
                                                      const float* __restrict__ bias,
                                                      const unsigned short* R,
                                                      unsigned short* Y,
                                                      int C_in, int dil) {
    const int tid = threadIdx.x;
    const int ib = blockIdx.x;
    const int work = (ib & 7) * 8 + (ib >> 3);   // [0,64)
    const int co0 = (work & 3) * 128;            // co fastest -> co-blocks co-located per XCD
    const int t0 = (work >> 2) * 128;
    const int b = blockIdx.z;
    const int back = (KS - 1) * dil;   // <= 64
    const int XWIN = 128 + back;

    __shared__ __align__(16) unsigned short sX[192 * 64];   // [row][ci64], swizzled slots
    __shared__ __align__(16) unsigned short sW[KS * 128 * 64];

    const int lane = tid & 63;
    const int wv = tid >> 6;
    const int wco = (wv & 1) * 64;
    const int wt = (wv >> 1) * 64;
    const int tl = lane & 15;
    const int ch = lane >> 4;

    f32x4 acc[4][4] = {};

    const unsigned short* Xb = X + ((size_t)b * PT_ + 64) * C_in;

    const unsigned short* xsrc[6];
#pragma unroll
    for (int k = 0; k < 6; ++k) {
        const int i = tid + k * 256;
        const int row = i >> 3, s = i & 7;
        int tg = t0 - back + row;                 // >= -64 (pad covers)
        if (tg >= T_) tg = T_ - 1;                // clamped rows are never read
        xsrc[k] = Xb + (size_t)tg * C_in + ((s ^ (row & 7)) << 3);
    }
    const unsigned short* wsrc[KS * 4];
#pragma unroll
    for (int k = 0; k < KS * 4; ++k) {
        const int i = tid + k * 256;
        const int row = i >> 3, s = i & 7;
        const int tap = row >> 7, rco = row & 127;
        wsrc[k] = Wt + ((size_t)(tap * 512 + co0 + rco)) * C_in + ((s ^ (row & 7)) << 3);
    }
    const int nx = XWIN * 8;   // X 16B slots (<= 1536)

    const int NC = C_in >> 6;
    for (int c = 0; c < NC; ++c) {
        if (c) __syncthreads();  // protect buffer from waves still reading chunk c-1
#pragma unroll
        for (int k = 0; k < 6; ++k) {
            const int i = tid + k * 256;
            if (i < nx) gload_lds16(xsrc[k] + c * 64, &sX[(i & ~63) * 8]);
        }
#pragma unroll
        for (int k = 0; k < KS * 4; ++k) {
            const int i = tid + k * 256;
            gload_lds16(wsrc[k] + c * 64, &sW[(i & ~63) * 8]);
        }
        __syncthreads();  // drains vmcnt(0): tile ready

#pragma unroll
        for (int tap = 0; tap < KS; ++tap) {
            const int tapoff = tap * dil;
#pragma unroll
            for (int ks = 0; ks < 2; ++ks) {
                const int j = ks * 4 + ch;
                bf16x8 a[4], bb[4];
#pragma unroll
                for (int m = 0; m < 4; ++m) {
                    const int wr = tap * 128 + wco + m * 16 + tl;
                    a[m] = *reinterpret_cast<const bf16x8*>(
                        &sW[wr * 64 + ((j ^ (wr & 7)) << 3)]);
                }
#pragma unroll
                for (int n = 0; n < 4; ++n) {
                    const int xr = wt + n * 16 + tl + tapoff;
                    bb[n] = *reinterpret_cast<const bf16x8*>(
                        &sX[xr * 64 + ((j ^ (xr & 7)) << 3)]);
                }
#pragma unroll
                for (int m = 0; m < 4; ++m)
#pragma unroll
                    for (int n = 0; n < 4; ++n)
                        acc[m][n] = __builtin_amdgcn_mfma_f32_16x16x32_bf16(a[m], bb[n], acc[m][n], 0, 0, 0);
            }
        }
    }

#pragma unroll
    for (int m = 0; m < 4; ++m) {
        const int co = co0 + wco + m * 16 + ch * 4;
        const float4 bv4 = *reinterpret_cast<const float4*>(&bias[co]);
#pragma unroll
        for (int n = 0; n < 4; ++n) {
            const int t = t0 + wt + n * 16 + tl;
            const size_t base = HROW(b, t) + co;
            float v[4];
            v[0] = acc[m][n][0] + bv4.x;
            v[1] = acc[m][n][1] + bv4.y;
            v[2] = acc[m][n][2] + bv4.z;
            v[3] = acc[m][n][3] + bv4.w;
            if (MODE >= 1) {
#pragma unroll
                for (int r = 0; r < 4; ++r) v[r] = gelu_f(v[r]);
            }
            if (MODE == 2) {
                const uint2 rr = *reinterpret_cast<const uint2*>(&R[base]);
                v[0] += bfu2f((unsigned short)(rr.x & 0xffffu));
                v[1] += bfu2f((unsigned short)(rr.x >> 16));
                v[2] += bfu2f((unsigned short)(rr.y & 0xffffu));
                v[3] += bfu2f((unsigned short)(rr.y >> 16));
            }
            uint2 o;
            o.x = (unsigned int)f2bf(v[0]) | ((unsigned int)f2bf(v[1]) << 16);
            o.y = (unsigned int)f2bf(v[2]) | ((unsigned int)f2bf(v[3]) << 16);
            *reinterpret_cast<uint2*>(&Y[base]) = o;
        }
    }
}

// -------- fused q + qk: block b computes q[b][:], then qkvec[b][:], qbk[b] --------
__global__ __launch_bounds__(512) void k_qfused(const unsigned short* __restrict__ h,
                                                const float* __restrict__ wq,
                                                const float* __restrict__ bq,
                                                const float* __restrict__ wk,
                                                const float* __restrict__ bk,
                                                float* __restrict__ qkvec,
                                                float* __restrict__ qbk) {
    const int b = blockIdx.x, tid = threadIdx.x;
    const int lane = tid & 63, wv = tid >> 6;
    __shared__ float zl[D_];
    __shared__ float qs[D_];
    __shared__ float red[8];
    if (tid < D_) zl[tid] = bfu2f(h[HROW(b, T_ - 1) + tid]);
    __syncthreads();
    for (int k = 0; k < 64; ++k) {
        const int d = wv * 64 + k;
        const float* row = wq + (size_t)d * D_ + lane * 8;
        float a = 0.0f;
#pragma unroll
        for (int j = 0; j < 8; ++j) a += row[j] * zl[lane * 8 + j];
#pragma unroll
        for (int off = 32; off; off >>= 1) a += __shfl_xor(a, off);
        if (lane == 0) qs[d] = a + bq[d];
    }
    __syncthreads();
    float acc = 0.0f;
#pragma unroll 8
    for (int d = 0; d < D_; ++d) acc += qs[d] * wk[(size_t)d * D_ + tid];
    qkvec[b * D_ + tid] = acc;
    float p = qs[tid] * bk[tid];
#pragma unroll
    for (int off = 32; off; off >>= 1) p += __shfl_xor(p, off);
    if (lane == 0) red[wv] = p;
    __syncthreads();
    if (tid == 0) {
        float s = 0.0f;
#pragma unroll
        for (int i = 0; i < 8; ++i) s += red[i];
        qbk[b] = s;
    }
}

// -------- scores[b,t] = (h[b,t,:] . qkvec[b,:] + qbk[b]) / sqrt(D), wave per t --------
__global__ __launch_bounds__(256) void k_scores(const unsigned short* __restrict__ h,
                                                const float* __restrict__ qkvec,
                                                const float* __restrict__ qbk,
                                                float* __restrict__ scores) {
    const int b = blockIdx.y;
    const int tid = threadIdx.x;
    __shared__ float qs[D_];
    qs[tid] = qkvec[b * D_ + tid];
    qs[tid + 256] = qkvec[b * D_ + tid + 256];
    __syncthreads();
    const int wvi = tid >> 6, lane = tid & 63;
    const int t = blockIdx.x * 4 + wvi;
    const uint4 v = *reinterpret_cast<const uint4*>(h + HROW(b, t) + lane * 8);
    const unsigned int w[4] = {v.x, v.y, v.z, v.w};
    float acc = 0.0f;
#pragma unroll
    for (int j = 0; j < 4; ++j) {
        acc += bfu2f((unsigned short)(w[j] & 0xffffu)) * qs[lane * 8 + 2 * j];
        acc += bfu2f((unsigned short)(w[j] >> 16)) * qs[lane * 8 + 2 * j + 1];
    }
    for (int off = 32; off; off >>= 1) acc += __shfl_down(acc, off);
    if (lane == 0) scores[b * T_ + t] = (acc + qbk[b]) * 0.04419417382415922f;
}

// -------- top-512 of 2048 via bitonic sort, then masked softmax weights --------
__global__ __launch_bounds__(1024) void k_topk(const float* __restrict__ scores,
                                               float* __restrict__ wts) {
    const int b = blockIdx.x;
    __shared__ float s[T_];
    __shared__ float v[T_];
    __shared__ float red[16];
    __shared__ float denom_s;
    for (int i = threadIdx.x; i < T_; i += 1024) {
        const float x = scores[b * T_ + i];
        s[i] = x; v[i] = x;
    }
    __syncthreads();
    for (unsigned kk = 2; kk <= T_; kk <<= 1) {
        for (unsigned j = kk >> 1; j > 0; j >>= 1) {
            for (unsigned i = threadIdx.x; i < T_; i += 1024) {
                const unsigned ixj = i ^ j;
                if (ixj > i) {
                    const float a = v[i], c2 = v[ixj];
                    const bool asc = ((i & kk) == 0);
                    if ((a > c2) == asc) { v[i] = c2; v[ixj] = a; }
                }
            }
            __syncthreads();
        }
    }
    const float thr = v[T_ - 512];
    const float mx = v[T_ - 1];
    float part = 0.0f;
    for (int i = threadIdx.x; i < T_; i += 1024) {
        const float x = s[i];
        if (x >= thr) part += expf(x - mx);
    }
    for (int off = 32; off; off >>= 1) part += __shfl_down(part, off);
    const int lane = threadIdx.x & 63, wv_ = threadIdx.x >> 6;
    if (lane == 0) red[wv_] = part;
    __syncthreads();
    if (threadIdx.x == 0) {
        float d = 0.0f;
        for (int i = 0; i < 16; ++i) d += red[i];
        denom_s = d;
    }
    __syncthreads();
    const float inv = 1.0f / denom_s;
    for (int i = threadIdx.x; i < T_; i += 1024) {
        const float x = s[i];
        wts[b * T_ + i] = (x >= thr) ? expf(x - mx) * inv : 0.0f;
    }
}

// -------- zv[b,c] = sum_t w[b,t]*h[b,t,c] (partial blocks + atomics) --------
__global__ __launch_bounds__(256) void k_zv(const unsigned short* __restrict__ h,
                                            const float* __restrict__ wts,
                                            float* __restrict__ zvb) {
    const int b = blockIdx.y;
    const int t0 = blockIdx.x * 256;
    const int tid = threadIdx.x;
    float a0 = 0.0f, a1 = 0.0f;
    for (int t = t0; t < t0 + 256; ++t) {
        const float w = wts[b * T_ + t];
        if (w != 0.0f) {
            const unsigned int v = *reinterpret_cast<const unsigned int*>(
                h + HROW(b, t) + tid * 2);
            a0 += w * bfu2f((unsigned short)(v & 0xffffu));
            a1 += w * bfu2f((unsigned short)(v >> 16));
        }
    }
    atomicAdd(&zvb[b * D_ + tid * 2], a0);
    atomicAdd(&zvb[b * D_ + tid * 2 + 1], a1);
}

// -------- fused u + out: block b computes u[b][:], then out[b][:] --------
__global__ __launch_bounds__(512) void k_ufused(const unsigned short* __restrict__ h,
                                                const float* __restrict__ zvb,
                                                const float* __restrict__ wv,
                                                const float* __restrict__ bv,
                                                const float* __restrict__ wp,
                                                const float* __restrict__ bp,
                                                float* __restrict__ out) {
    const int b = blockIdx.x, tid = threadIdx.x;
    const int lane = tid & 63, wvi = tid >> 6;
    __shared__ float zvs[D_];
    __shared__ float us[D_];
    if (tid < D_) zvs[tid] = zvb[b * D_ + tid];
    __syncthreads();
    for (int k = 0; k < 64; ++k) {
        const int e = wvi * 64 + k;
        const float* row = wv + (size_t)e * D_ + lane * 8;
        float a = 0.0f;
#pragma unroll
        for (int j = 0; j < 8; ++j) a += row[j] * zvs[lane * 8 + j];
#pragma unroll
        for (int off = 32; off; off >>= 1) a += __shfl_xor(a, off);
        if (lane == 0) us[e] = a + bv[e] + bfu2f(h[HROW(b, T_ - 1) + e]);
    }
    __syncthreads();
    for (int k = 0; k < 64; ++k) {
        const int d = wvi * 64 + k;
        const float* row = wp + (size_t)d * D_ + lane * 8;
        float a = 0.0f;
#pragma unroll
        for (int j = 0; j < 8; ++j) a += row[j] * us[lane * 8 + j];
#pragma unroll
        for (int off = 32; off; off >>= 1) a += __shfl_xor(a, off);
        if (lane == 0) out[b * D_ + d] = a + bp[d];
    }
}

extern "C" void kernel_launch(void* const* d_in, const int* in_sizes, int n_in,
                              void* d_out, int out_size, void* d_ws, size_t ws_size,
                              hipStream_t stream) {
    const float* x    = (const float*)d_in[0];
    const float* c1w0 = (const float*)d_in[1];
    const float* c1b0 = (const float*)d_in[2];
    const float* c2w0 = (const float*)d_in[3];
    const float* c2b0 = (const float*)d_in[4];
    const float* resw = (const float*)d_in[5];
    const float* resb = (const float*)d_in[6];
    const float* c1w  = (const float*)d_in[7];
    const float* c1b  = (const float*)d_in[8];
    const float* c2w  = (const float*)d_in[9];
    const float* c2b  = (const float*)d_in[10];
    const float* wq   = (const float*)d_in[11];
    const float* bq   = (const float*)d_in[12];
    const float* wk   = (const float*)d_in[13];
    const float* bk   = (const float*)d_in[14];
    const float* wvp  = (const float*)d_in[15];
    const float* bv   = (const float*)d_in[16];
    const float* wp   = (const float*)d_in[17];
    const float* bp   = (const float*)d_in[18];
    float* out = (float*)d_out;

    unsigned short* ws16 = (unsigned short*)d_ws;
    unsigned short* xb   = ws16;                           // B*PT*64
    unsigned short* bufA = xb + (size_t)B_ * PT_ * DIN_;   // B*PT*512
    unsigned short* bufB = bufA + (size_t)B_ * PT_ * D_;   // B*PT*512
    unsigned short* wRes = bufB + (size_t)B_ * PT_ * D_;   // 512*64
    unsigned short* wC10 = wRes + 512 * 64;                // 3*512*64
    unsigned short* wC20 = wC10 + 3 * 512 * 64;            // 3*512*512
    unsigned short* wC1  = wC20 + 3 * 512 * 512;           // 5*3*512*512
    unsigned short* wC2  = wC1 + (size_t)5 * 3 * 512 * 512;
    float* fws  = (float*)(wC2 + (size_t)5 * 3 * 512 * 512);
    float* qkvec = fws;                 // 8*512 (direct store)
    float* qbk   = qkvec + B_ * D_;     // 8     (direct store)
    float* zvb   = qbk + 8;             // 8*512 (zeroed in k_setup)
    float* sc    = zvb + B_ * D_;       // 8*2048
    float* wts   = sc + B_ * T_;        // 8*2048

    const int nsetup = B_ * 64 * (DIN_ + 2 * D_) + B_ * T_ * DIN_ + B_ * D_;
    k_setup<<<dim3((nsetup + 255) / 256), 256, 0, stream>>>(x, xb, bufA, bufB, zvb);
    k_wcvt_all<<<dim3(768, 13), 256, 0, stream>>>(resw, c1w0, c2w0, c1w, c2w,
                                                  wRes, wC10, wC20, wC1, wC2);

    const dim3 cgrid(64, 1, B_);
    // block 0: dual dispatch {residual 1x1 -> bufA  ||  conv1 -> bufB}, then conv2+res -> bufA
    k_conv_b0<<<dim3(64, 2, B_), 256, 0, stream>>>(xb, wRes, resb, wC10, c1b0, bufA, bufB);
    k_conv_mfma<3, 2><<<cgrid, 256, 0, stream>>>(bufB, wC20, c2b0, bufA, bufA, D_, 1);
    // blocks 1..5 (dilations 2,4,8,16,32), identity residual (in place)
    for (int i = 0; i < 5; ++i) {
        const int dil = 2 << i;
        k_conv_mfma<3, 1><<<cgrid, 256, 0, stream>>>(bufA, wC1 + (size_t)i * 3 * 512 * 512,
                                                     c1b + i * D_, nullptr, bufB, D_, dil);
        k_conv_mfma<3, 2><<<cgrid, 256, 0, stream>>>(bufB, wC2 + (size_t)i * 3 * 512 * 512,
                                                     c2b + i * D_, bufA, bufA, D_, dil);
    }

    k_qfused<<<B_, 512, 0, stream>>>(bufA, wq, bq, wk, bk, qkvec, qbk);
    k_scores<<<dim3(T_ / 4, B_), 256, 0, stream>>>(bufA, qkvec, qbk, sc);
    k_topk<<<B_, 1024, 0, stream>>>(sc, wts);
    k_zv<<<dim3(T_ / 256, B_), 256, 0, stream>>>(bufA, wts, zvb);
    k_ufused<<<B_, 512, 0, stream>>>(bufA, zvb, wvp, bv, wp, bp, out);
}

// Round 16
// 457.099 us; speedup vs baseline: 1.3008x; 1.3008x over previous
//
#include <hip/hip_runtime.h>
#include <hip/hip_bf16.h>
#include <math.h>

#define B_ 8
#define T_ 2048
#define PT_ 2112   // T_ + 64 zero-pad rows at the start of each batch
#define DIN_ 64
#define D_ 512

typedef __attribute__((ext_vector_type(8))) short bf16x8;
typedef __attribute__((ext_vector_type(4))) float f32x4;

#define HROW(b, t) (((size_t)(b) * PT_ + 64 + (t)) * D_)

__device__ __forceinline__ float gelu_f(float x) {
    return 0.5f * x * (1.0f + erff(x * 0.70710678118654752440f));
}
__device__ __forceinline__ float bfu2f(unsigned short u) {
    union { float f; unsigned int i; } v; v.i = ((unsigned int)u) << 16; return v.f;
}
__device__ __forceinline__ unsigned short f2bf(float f) {
    unsigned int x = __float_as_uint(f);
    return (unsigned short)((x + 0x7FFFu + ((x >> 16) & 1u)) >> 16);
}
// async global->LDS, 16B per lane; lds dest is wave-uniform base (+ lane*16 by HW)
__device__ __forceinline__ void gload_lds16(const void* g, void* l) {
    __builtin_amdgcn_global_load_lds(
        (const __attribute__((address_space(1))) void*)g,
        (__attribute__((address_space(3))) void*)l, 16, 0, 0);
}

// -------- fused setup: zero pads + fp32->bf16 input + zero qkvec/qbk/zvb --------
__global__ __launch_bounds__(256) void k_setup(const float* __restrict__ x,
                                               unsigned short* __restrict__ xb,
                                               unsigned short* bufA,
                                               unsigned short* bufB,
                                               float* zbuf /* qkvec|qbk|zvb */) {
    const int NX = B_ * 64 * DIN_;
    const int NA = B_ * 64 * D_;
    const int NC = B_ * T_ * DIN_;
    const int NZ = 2 * B_ * D_ + 8;
    int i = blockIdx.x * 256 + threadIdx.x;
    if (i < NX) {
        const int b = i / (64 * DIN_), r = i - b * (64 * DIN_);
        xb[(size_t)b * PT_ * DIN_ + r] = 0;
        return;
    }
    i -= NX;
    if (i < NA) {
        const int b = i / (64 * D_), r = i - b * (64 * D_);
        bufA[(size_t)b * PT_ * D_ + r] = 0;
        return;
    }
    i -= NA;
    if (i < NA) {
        const int b = i / (64 * D_), r = i - b * (64 * D_);
        bufB[(size_t)b * PT_ * D_ + r] = 0;
        return;
    }
    i -= NA;
    if (i < NC) {
        const int b = i / (T_ * DIN_);
        const int r = i - b * (T_ * DIN_);
        xb[((size_t)b * PT_ + 64) * DIN_ + r] = f2bf(x[i]);
        return;
    }
    i -= NC;
    if (i < NZ) zbuf[i] = 0.0f;
}

// -------- fused weight convert+transpose for ALL 13 conv weight tensors --------
__global__ __launch_bounds__(256) void k_wcvt_all(const float* resw, const float* c1w0,
                                                  const float* c2w0, const float* c1w,
                                                  const float* c2w,
                                                  unsigned short* wRes, unsigned short* wC10,
                                                  unsigned short* wC20, unsigned short* wC1,
                                                  unsigned short* wC2) {
    const int l = blockIdx.y;
    const float* src;
    unsigned short* dst;
    int C_in, KS;
    if (l == 0)      { src = resw; dst = wRes; C_in = 64;  KS = 1; }
    else if (l == 1) { src = c1w0; dst = wC10; C_in = 64;  KS = 3; }
    else if (l == 2) { src = c2w0; dst = wC20; C_in = 512; KS = 3; }
    else if (l <= 7) { src = c1w + (size_t)(l - 3) * 512 * 512 * 3;
                       dst = wC1 + (size_t)(l - 3) * 3 * 512 * 512; C_in = 512; KS = 3; }
    else             { src = c2w + (size_t)(l - 8) * 512 * 512 * 3;
                       dst = wC2 + (size_t)(l - 8) * 3 * 512 * 512; C_in = 512; KS = 3; }
    const int n = 512 * C_in * KS;
    for (int i = blockIdx.x * 256 + threadIdx.x; i < n; i += gridDim.x * 256) {
        const int ci = i % C_in;
        const int r = i / C_in;
        const int co = r & 511;
        const int tap = r >> 9;
        dst[i] = f2bf(src[((size_t)co * C_in + ci) * KS + tap]);
    }
}

// -------- block-0 dual conv: y=0 -> 1x1 residual->bufA; y=1 -> 3-tap gelu->bufB --------
__global__ __launch_bounds__(256, 2) void k_conv_b0(const unsigned short* __restrict__ X,
                                                    const unsigned short* __restrict__ wRes,
                                                    const float* __restrict__ resb,
                                                    const unsigned short* __restrict__ wC10,
                                                    const float* __restrict__ c1b0,
                                                    unsigned short* bufA,
                                                    unsigned short* bufB) {
    const int tid = threadIdx.x;
    const int ib = blockIdx.x;
    const int work = (ib & 7) * 8 + (ib >> 3);
    const int co0 = (work & 3) * 128;
    const int t0 = (work >> 2) * 128;
    const int b = blockIdx.z;
    const int y = blockIdx.y;
    const int nks = y ? 3 : 1;
    const unsigned short* Wt = y ? wC10 : wRes;
    const float* bias = y ? c1b0 : resb;
    unsigned short* Y = y ? bufB : bufA;
    const int back = nks - 1;            // dil=1
    const int nx = (128 + back) * 8;

    __shared__ __align__(16) unsigned short sX[192 * 64];
    __shared__ __align__(16) unsigned short sW[3 * 128 * 64];

    const int lane = tid & 63;
    const int wv = tid >> 6;
    const int wco = (wv & 1) * 64;
    const int wt = (wv >> 1) * 64;
    const int tl = lane & 15;
    const int ch = lane >> 4;

    f32x4 acc[4][4] = {};

    const unsigned short* Xb = X + ((size_t)b * PT_ + 64) * DIN_;

#pragma unroll
    for (int k = 0; k < 6; ++k) {
        const int i = tid + k * 256;
        if (i < nx) {
            const int row = i >> 3, s = i & 7;
            int tg = t0 - back + row;
            if (tg >= T_) tg = T_ - 1;
            gload_lds16(Xb + (size_t)tg * DIN_ + ((s ^ (row & 7)) << 3), &sX[(i & ~63) * 8]);
        }
    }
    for (int k = 0; k < nks * 4; ++k) {
        const int i = tid + k * 256;
        const int row = i >> 3, s = i & 7;
        const int tap = row >> 7, rco = row & 127;
        gload_lds16(Wt + ((size_t)(tap * 512 + co0 + rco)) * DIN_ + ((s ^ (row & 7)) << 3),
                    &sW[(i & ~63) * 8]);
    }
    __syncthreads();

    for (int tap = 0; tap < nks; ++tap) {
        const int tapoff = tap;
#pragma unroll
        for (int kh = 0; kh < 2; ++kh) {
            const int j = kh * 4 + ch;
            bf16x8 a[4], bb[4];
#pragma unroll
            for (int m = 0; m < 4; ++m) {
                const int wr = tap * 128 + wco + m * 16 + tl;
                a[m] = *reinterpret_cast<const bf16x8*>(&sW[wr * 64 + ((j ^ (wr & 7)) << 3)]);
            }
#pragma unroll
            for (int n = 0; n < 4; ++n) {
                const int xr = wt + n * 16 + tl + tapoff;
                bb[n] = *reinterpret_cast<const bf16x8*>(&sX[xr * 64 + ((j ^ (xr & 7)) << 3)]);
            }
#pragma unroll
            for (int m = 0; m < 4; ++m)
#pragma unroll
                for (int n = 0; n < 4; ++n)
                    acc[m][n] = __builtin_amdgcn_mfma_f32_16x16x32_bf16(a[m], bb[n], acc[m][n], 0, 0, 0);
        }
    }

#pragma unroll
    for (int m = 0; m < 4; ++m) {
        const int co = co0 + wco + m * 16 + ch * 4;
        const float4 bv4 = *reinterpret_cast<const float4*>(&bias[co]);
#pragma unroll
        for (int n = 0; n < 4; ++n) {
            const int t = t0 + wt + n * 16 + tl;
            const size_t base = HROW(b, t) + co;
            float v[4];
            v[0] = acc[m][n][0] + bv4.x;
            v[1] = acc[m][n][1] + bv4.y;
            v[2] = acc[m][n][2] + bv4.z;
            v[3] = acc[m][n][3] + bv4.w;
            if (y) {
#pragma unroll
                for (int r = 0; r < 4; ++r) v[r] = gelu_f(v[r]);
            }
            uint2 o;
            o.x = (unsigned int)f2bf(v[0]) | ((unsigned int)f2bf(v[1]) << 16);
            o.y = (unsigned int)f2bf(v[2]) | ((unsigned int)f2bf(v[3]) << 16);
            *reinterpret_cast<uint2*>(&Y[base]) = o;
        }
    }
}

// -------- causal dilated conv via bf16 MFMA implicit GEMM (R11, measured best) --------
template <int KS, int MODE>
__global__ __launch_bounds__(256, 2) void k_conv_mfma(const unsigned short* __restrict__ X,
                                                      const unsigned short* __restrict__ Wt,
                                                      const float* __restrict__ bias,
                                                      const unsigned short* R,
                                                      unsigned short* Y,
                                                      int C_in, int dil) {
    const int tid = threadIdx.x;
    const int ib = blockIdx.x;
    const int work = (ib & 7) * 8 + (ib >> 3);   // [0,64)
    const int co0 = (work & 3) * 128;            // co fastest -> co-blocks co-located per XCD
    const int t0 = (work >> 2) * 128;
    const int b = blockIdx.z;
    const int back = (KS - 1) * dil;   // <= 64
    const int XWIN = 128 + back;

    __shared__ __align__(16) unsigned short sX[192 * 64];   // [row][ci64], swizzled slots
    __shared__ __align__(16) unsigned short sW[KS * 128 * 64];

    const int lane = tid & 63;
    const int wv = tid >> 6;
    const int wco = (wv & 1) * 64;
    const int wt = (wv >> 1) * 64;
    const int tl = lane & 15;
    const int ch = lane >> 4;

    f32x4 acc[4][4] = {};

    const unsigned short* Xb = X + ((size_t)b * PT_ + 64) * C_in;

    const unsigned short* xsrc[6];
#pragma unroll
    for (int k = 0; k < 6; ++k) {
        const int i = tid + k * 256;
        const int row = i >> 3, s = i & 7;
        int tg = t0 - back + row;                 // >= -64 (pad covers)
        if (tg >= T_) tg = T_ - 1;                // clamped rows are never read
        xsrc[k] = Xb + (size_t)tg * C_in + ((s ^ (row & 7)) << 3);
    }
    const unsigned short* wsrc[KS * 4];
#pragma unroll
    for (int k = 0; k < KS * 4; ++k) {
        const int i = tid + k * 256;
        const int row = i >> 3, s = i & 7;
        const int tap = row >> 7, rco = row & 127;
        wsrc[k] = Wt + ((size_t)(tap * 512 + co0 + rco)) * C_in + ((s ^ (row & 7)) << 3);
    }
    const int nx = XWIN * 8;   // X 16B slots (<= 1536)

    const int NC = C_in >> 6;
    for (int c = 0; c < NC; ++c) {
        if (c) __syncthreads();  // protect buffer from waves still reading chunk c-1
#pragma unroll
        for (int k = 0; k < 6; ++k) {
            const int i = tid + k * 256;
            if (i < nx) gload_lds16(xsrc[k] + c * 64, &sX[(i & ~63) * 8]);
        }
#pragma unroll
        for (int k = 0; k < KS * 4; ++k) {
            const int i = tid + k * 256;
            gload_lds16(wsrc[k] + c * 64, &sW[(i & ~63) * 8]);
        }
        __syncthreads();  // drains vmcnt(0): tile ready

#pragma unroll
        for (int tap = 0; tap < KS; ++tap) {
            const int tapoff = tap * dil;
#pragma unroll
            for (int ks = 0; ks < 2; ++ks) {
                const int j = ks * 4 + ch;
                bf16x8 a[4], bb[4];
#pragma unroll
                for (int m = 0; m < 4; ++m) {
                    const int wr = tap * 128 + wco + m * 16 + tl;
                    a[m] = *reinterpret_cast<const bf16x8*>(
                        &sW[wr * 64 + ((j ^ (wr & 7)) << 3)]);
                }
#pragma unroll
                for (int n = 0; n < 4; ++n) {
                    const int xr = wt + n * 16 + tl + tapoff;
                    bb[n] = *reinterpret_cast<const bf16x8*>(
                        &sX[xr * 64 + ((j ^ (xr & 7)) << 3)]);
                }
#pragma unroll
                for (int m = 0; m < 4; ++m)
#pragma unroll
                    for (int n = 0; n < 4; ++n)
                        acc[m][n] = __builtin_amdgcn_mfma_f32_16x16x32_bf16(a[m], bb[n], acc[m][n], 0, 0, 0);
            }
        }
    }

#pragma unroll
    for (int m = 0; m < 4; ++m) {
        const int co = co0 + wco + m * 16 + ch * 4;
        const float4 bv4 = *reinterpret_cast<const float4*>(&bias[co]);
#pragma unroll
        for (int n = 0; n < 4; ++n) {
            const int t = t0 + wt + n * 16 + tl;
            const size_t base = HROW(b, t) + co;
            float v[4];
            v[0] = acc[m][n][0] + bv4.x;
            v[1] = acc[m][n][1] + bv4.y;
            v[2] = acc[m][n][2] + bv4.z;
            v[3] = acc[m][n][3] + bv4.w;
            if (MODE >= 1) {
#pragma unroll
                for (int r = 0; r < 4; ++r) v[r] = gelu_f(v[r]);
            }
            if (MODE == 2) {
                const uint2 rr = *reinterpret_cast<const uint2*>(&R[base]);
                v[0] += bfu2f((unsigned short)(rr.x & 0xffffu));
                v[1] += bfu2f((unsigned short)(rr.x >> 16));
                v[2] += bfu2f((unsigned short)(rr.y & 0xffffu));
                v[3] += bfu2f((unsigned short)(rr.y >> 16));
            }
            uint2 o;
            o.x = (unsigned int)f2bf(v[0]) | ((unsigned int)f2bf(v[1]) << 16);
            o.y = (unsigned int)f2bf(v[2]) | ((unsigned int)f2bf(v[3]) << 16);
            *reinterpret_cast<uint2*>(&Y[base]) = o;
        }
    }
}

// -------- q[b][d] = bq[d] + wq[d,:] . z_last[b,:]; wave per d, all 8 b --------
__global__ __launch_bounds__(256) void k_q(const unsigned short* __restrict__ h,
                                           const float* __restrict__ wq,
                                           const float* __restrict__ bq,
                                           float* __restrict__ q) {
    __shared__ float zs[B_ * D_];
    const int tid = threadIdx.x;
    for (int i = tid; i < B_ * D_; i += 256) {
        const int b = i >> 9, c = i & 511;
        zs[i] = bfu2f(h[HROW(b, T_ - 1) + c]);
    }
    __syncthreads();
    const int wvi = tid >> 6, lane = tid & 63;
    const int d = blockIdx.x * 4 + wvi;
    const float* wr = wq + (size_t)d * D_ + lane * 8;
    float w8[8];
#pragma unroll
    for (int j = 0; j < 8; ++j) w8[j] = wr[j];
    float acc[B_];
#pragma unroll
    for (int b = 0; b < B_; ++b) {
        float a = 0.0f;
#pragma unroll
        for (int j = 0; j < 8; ++j) a += w8[j] * zs[b * D_ + lane * 8 + j];
        acc[b] = a;
    }
#pragma unroll
    for (int off = 32; off; off >>= 1) {
#pragma unroll
        for (int b = 0; b < B_; ++b) acc[b] += __shfl_xor(acc[b], off);
    }
    if (lane == 0) {
#pragma unroll
        for (int b = 0; b < B_; ++b) q[b * D_ + d] = acc[b] + bq[d];
    }
}

// -------- qkvec[b][c] += sum_{d in chunk} q[b][d]*wk[d][c]; + qbk partials --------
__global__ __launch_bounds__(512) void k_qk(const float* __restrict__ q,
                                            const float* __restrict__ wk,
                                            const float* __restrict__ bk,
                                            float* __restrict__ qkvec,
                                            float* __restrict__ qbk) {
    const int b = blockIdx.y, dc = blockIdx.x;
    const int tid = threadIdx.x;
    __shared__ float qs[64];
    if (tid < 64) qs[tid] = q[b * D_ + dc * 64 + tid];
    __syncthreads();
    float acc = 0.0f;
    const float* wbase = wk + (size_t)(dc * 64) * D_ + tid;
#pragma unroll 8
    for (int d = 0; d < 64; ++d) acc += qs[d] * wbase[(size_t)d * D_];
    atomicAdd(&qkvec[b * D_ + tid], acc);
    if (tid < 64) {
        float p = qs[tid] * bk[dc * 64 + tid];
#pragma unroll
        for (int off = 32; off; off >>= 1) p += __shfl_xor(p, off);
        if (tid == 0) atomicAdd(&qbk[b], p);
    }
}

// -------- scores[b,t] = (h[b,t,:] . qkvec[b,:] + qbk[b]) / sqrt(D), wave per t --------
__global__ __launch_bounds__(256) void k_scores(const unsigned short* __restrict__ h,
                                                const float* __restrict__ qkvec,
                                                const float* __restrict__ qbk,
                                                float* __restrict__ scores) {
    const int b = blockIdx.y;
    const int tid = threadIdx.x;
    __shared__ float qs[D_];
    qs[tid] = qkvec[b * D_ + tid];
    qs[tid + 256] = qkvec[b * D_ + tid + 256];
    __syncthreads();
    const int wvi = tid >> 6, lane = tid & 63;
    const int t = blockIdx.x * 4 + wvi;
    const uint4 v = *reinterpret_cast<const uint4*>(h + HROW(b, t) + lane * 8);
    const unsigned int w[4] = {v.x, v.y, v.z, v.w};
    float acc = 0.0f;
#pragma unroll
    for (int j = 0; j < 4; ++j) {
        acc += bfu2f((unsigned short)(w[j] & 0xffffu)) * qs[lane * 8 + 2 * j];
        acc += bfu2f((unsigned short)(w[j] >> 16)) * qs[lane * 8 + 2 * j + 1];
    }
    for (int off = 32; off; off >>= 1) acc += __shfl_down(acc, off);
    if (lane == 0) scores[b * T_ + t] = (acc + qbk[b]) * 0.04419417382415922f;
}

// -------- top-512 of 2048 via bitonic sort, then masked softmax weights --------
__global__ __launch_bounds__(1024) void k_topk(const float* __restrict__ scores,
                                               float* __restrict__ wts) {
    const int b = blockIdx.x;
    __shared__ float s[T_];
    __shared__ float v[T_];
    __shared__ float red[16];
    __shared__ float denom_s;
    for (int i = threadIdx.x; i < T_; i += 1024) {
        const float x = scores[b * T_ + i];
        s[i] = x; v[i] = x;
    }
    __syncthreads();
    for (unsigned kk = 2; kk <= T_; kk <<= 1) {
        for (unsigned j = kk >> 1; j > 0; j >>= 1) {
            for (unsigned i = threadIdx.x; i < T_; i += 1024) {
                const unsigned ixj = i ^ j;
                if (ixj > i) {
                    const float a = v[i], c2 = v[ixj];
                    const bool asc = ((i & kk) == 0);
                    if ((a > c2) == asc) { v[i] = c2; v[ixj] = a; }
                }
            }
            __syncthreads();
        }
    }
    const float thr = v[T_ - 512];
    const float mx = v[T_ - 1];
    float part = 0.0f;
    for (int i = threadIdx.x; i < T_; i += 1024) {
        const float x = s[i];
        if (x >= thr) part += expf(x - mx);
    }
    for (int off = 32; off; off >>= 1) part += __shfl_down(part, off);
    const int lane = threadIdx.x & 63, wv_ = threadIdx.x >> 6;
    if (lane == 0) red[wv_] = part;
    __syncthreads();
    if (threadIdx.x == 0) {
        float d = 0.0f;
        for (int i = 0; i < 16; ++i) d += red[i];
        denom_s = d;
    }
    __syncthreads();
    const float inv = 1.0f / denom_s;
    for (int i = threadIdx.x; i < T_; i += 1024) {
        const float x = s[i];
        wts[b * T_ + i] = (x >= thr) ? expf(x - mx) * inv : 0.0f;
    }
}

// -------- zv[b,c] = sum_t w[b,t]*h[b,t,c] (partial blocks + atomics) --------
__global__ __launch_bounds__(256) void k_zv(const unsigned short* __restrict__ h,
                                            const float* __restrict__ wts,
                                            float* __restrict__ zvb) {
    const int b = blockIdx.y;
    const int t0 = blockIdx.x * 256;
    const int tid = threadIdx.x;
    float a0 = 0.0f, a1 = 0.0f;
    for (int t = t0; t < t0 + 256; ++t) {
        const float w = wts[b * T_ + t];
        if (w != 0.0f) {
            const unsigned int v = *reinterpret_cast<const unsigned int*>(
                h + HROW(b, t) + tid * 2);
            a0 += w * bfu2f((unsigned short)(v & 0xffffu));
            a1 += w * bfu2f((unsigned short)(v >> 16));
        }
    }
    atomicAdd(&zvb[b * D_ + tid * 2], a0);
    atomicAdd(&zvb[b * D_ + tid * 2 + 1], a1);
}

// -------- u[b][e] = bv[e] + z_last[b][e] + wv[e,:] . zv[b,:]; wave per e --------
__global__ __launch_bounds__(256) void k_u(const unsigned short* __restrict__ h,
                                           const float* __restrict__ zvb,
                                           const float* __restrict__ wv,
                                           const float* __restrict__ bv,
                                           float* __restrict__ u) {
    __shared__ float zs[B_ * D_];
    const int tid = threadIdx.x;
    for (int i = tid; i < B_ * D_; i += 256) zs[i] = zvb[i];
    __syncthreads();
    const int wvi = tid >> 6, lane = tid & 63;
    const int e = blockIdx.x * 4 + wvi;
    const float* wr = wv + (size_t)e * D_ + lane * 8;
    float w8[8];
#pragma unroll
    for (int j = 0; j < 8; ++j) w8[j] = wr[j];
    float acc[B_];
#pragma unroll
    for (int b = 0; b < B_; ++b) {
        float a = 0.0f;
#pragma unroll
        for (int j = 0; j < 8; ++j) a += w8[j] * zs[b * D_ + lane * 8 + j];
        acc[b] = a;
    }
#pragma unroll
    for (int off = 32; off; off >>= 1) {
#pragma unroll
        for (int b = 0; b < B_; ++b) acc[b] += __shfl_xor(acc[b], off);
    }
    if (lane == 0) {
#pragma unroll
        for (int b = 0; b < B_; ++b)
            u[b * D_ + e] = acc[b] + bv[e] + bfu2f(h[HROW(b, T_ - 1) + e]);
    }
}

// -------- out[b][d] = bp[d] + wp[d,:] . u[b,:]; wave per d --------
__global__ __launch_bounds__(256) void k_out(const float* __restrict__ u,
                                             const float* __restrict__ wp,
                                             const float* __restrict__ bp,
                                             float* __restrict__ out) {
    __shared__ float us[B_ * D_];
    const int tid = threadIdx.x;
    for (int i = tid; i < B_ * D_; i += 256) us[i] = u[i];
    __syncthreads();
    const int wvi = tid >> 6, lane = tid & 63;
    const int d = blockIdx.x * 4 + wvi;
    const float* wr = wp + (size_t)d * D_ + lane * 8;
    float w8[8];
#pragma unroll
    for (int j = 0; j < 8; ++j) w8[j] = wr[j];
    float acc[B_];
#pragma unroll
    for (int b = 0; b < B_; ++b) {
        float a = 0.0f;
#pragma unroll
        for (int j = 0; j < 8; ++j) a += w8[j] * us[b * D_ + lane * 8 + j];
        acc[b] = a;
    }
#pragma unroll
    for (int off = 32; off; off >>= 1) {
#pragma unroll
        for (int b = 0; b < B_; ++b) acc[b] += __shfl_xor(acc[b], off);
    }
    if (lane == 0) {
#pragma unroll
        for (int b = 0; b < B_; ++b) out[b * D_ + d] = acc[b] + bp[d];
    }
}

extern "C" void kernel_launch(void* const* d_in, const int* in_sizes, int n_in,
                              void* d_out, int out_size, void* d_ws, size_t ws_size,
                              hipStream_t stream) {
    const float* x    = (const float*)d_in[0];
    const float* c1w0 = (const float*)d_in[1];
    const float* c1b0 = (const float*)d_in[2];
    const float* c2w0 = (const float*)d_in[3];
    const float* c2b0 = (const float*)d_in[4];
    const float* resw = (const float*)d_in[5];
    const float* resb = (const float*)d_in[6];
    const float* c1w  = (const float*)d_in[7];
    const float* c1b  = (const float*)d_in[8];
    const float* c2w  = (const float*)d_in[9];
    const float* c2b  = (const float*)d_in[10];
    const float* wq   = (const float*)d_in[11];
    const float* bq   = (const float*)d_in[12];
    const float* wk   = (const float*)d_in[13];
    const float* bk   = (const float*)d_in[14];
    const float* wvp  = (const float*)d_in[15];
    const float* bv   = (const float*)d_in[16];
    const float* wp   = (const float*)d_in[17];
    const float* bp   = (const float*)d_in[18];
    float* out = (float*)d_out;

    unsigned short* ws16 = (unsigned short*)d_ws;
    unsigned short* xb   = ws16;                           // B*PT*64
    unsigned short* bufA = xb + (size_t)B_ * PT_ * DIN_;   // B*PT*512
    unsigned short* bufB = bufA + (size_t)B_ * PT_ * D_;   // B*PT*512
    unsigned short* wRes = bufB + (size_t)B_ * PT_ * D_;   // 512*64
    unsigned short* wC10 = wRes + 512 * 64;                // 3*512*64
    unsigned short* wC20 = wC10 + 3 * 512 * 64;            // 3*512*512
    unsigned short* wC1  = wC20 + 3 * 512 * 512;           // 5*3*512*512
    unsigned short* wC2  = wC1 + (size_t)5 * 3 * 512 * 512;
    float* fws  = (float*)(wC2 + (size_t)5 * 3 * 512 * 512);
    float* qv    = fws;                 // 8*512 (no init)
    float* qkvec = qv + B_ * D_;        // 8*512 zero (k_setup)
    float* qbk   = qkvec + B_ * D_;     // 8     zero (k_setup)
    float* zvb   = qbk + 8;             // 8*512 zero (k_setup)
    float* uacc  = zvb + B_ * D_;       // 8*512 (no init)
    float* sc    = uacc + B_ * D_;      // 8*2048
    float* wts   = sc + B_ * T_;        // 8*2048

    const int nsetup = B_ * 64 * (DIN_ + 2 * D_) + B_ * T_ * DIN_ + 2 * B_ * D_ + 8;
    k_setup<<<dim3((nsetup + 255) / 256), 256, 0, stream>>>(x, xb, bufA, bufB, qkvec);
    k_wcvt_all<<<dim3(768, 13), 256, 0, stream>>>(resw, c1w0, c2w0, c1w, c2w,
                                                  wRes, wC10, wC20, wC1, wC2);

    const dim3 cgrid(64, 1, B_);
    // block 0: dual dispatch {residual 1x1 -> bufA || conv1 -> bufB}, then conv2+res -> bufA
    k_conv_b0<<<dim3(64, 2, B_), 256, 0, stream>>>(xb, wRes, resb, wC10, c1b0, bufA, bufB);
    k_conv_mfma<3, 2><<<cgrid, 256, 0, stream>>>(bufB, wC20, c2b0, bufA, bufA, D_, 1);
    // blocks 1..5 (dilations 2,4,8,16,32), identity residual (in place)
    for (int i = 0; i < 5; ++i) {
        const int dil = 2 << i;
        k_conv_mfma<3, 1><<<cgrid, 256, 0, stream>>>(bufA, wC1 + (size_t)i * 3 * 512 * 512,
                                                     c1b + i * D_, nullptr, bufB, D_, dil);
        k_conv_mfma<3, 2><<<cgrid, 256, 0, stream>>>(bufB, wC2 + (size_t)i * 3 * 512 * 512,
                                                     c2b + i * D_, bufA, bufA, D_, dil);
    }

    k_q<<<128, 256, 0, stream>>>(bufA, wq, bq, qv);
    k_qk<<<dim3(8, 8), 512, 0, stream>>>(qv, wk, bk, qkvec, qbk);
    k_scores<<<dim3(T_ / 4, B_), 256, 0, stream>>>(bufA, qkvec, qbk, sc);
    k_topk<<<B_, 1024, 0, stream>>>(sc, wts);
    k_zv<<<dim3(T_ / 256, B_), 256, 0, stream>>>(bufA, wts, zvb);
    k_u<<<128, 256, 0, stream>>>(bufA, zvb, wvp, bv, uacc);
    k_out<<<128, 256, 0, stream>>>(uacc, wp, bp, out);
}

// Round 17
// 452.991 us; speedup vs baseline: 1.3126x; 1.0091x over previous
//
#include <hip/hip_runtime.h>
#include <hip/hip_bf16.h>
#include <math.h>

#define B_ 8
#define T_ 2048
#define PT_ 2112   // T_ + 64 zero-pad rows at the start of each batch
#define DIN_ 64
#define D_ 512

typedef __attribute__((ext_vector_type(8))) short bf16x8;
typedef __attribute__((ext_vector_type(4))) float f32x4;

#define HROW(b, t) (((size_t)(b) * PT_ + 64 + (t)) * D_)

__device__ __forceinline__ float gelu_f(float x) {
    return 0.5f * x * (1.0f + erff(x * 0.70710678118654752440f));
}
__device__ __forceinline__ float bfu2f(unsigned short u) {
    union { float f; unsigned int i; } v; v.i = ((unsigned int)u) << 16; return v.f;
}
__device__ __forceinline__ unsigned short f2bf(float f) {
    unsigned int x = __float_as_uint(f);
    return (unsigned short)((x + 0x7FFFu + ((x >> 16) & 1u)) >> 16);
}
// async global->LDS, 16B per lane; lds dest is wave-uniform base (+ lane*16 by HW)
__device__ __forceinline__ void gload_lds16(const void* g, void* l) {
    __builtin_amdgcn_global_load_lds(
        (const __attribute__((address_space(1))) void*)g,
        (__attribute__((address_space(3))) void*)l, 16, 0, 0);
}

// -------- fused setup: zero pads + fp32->bf16 input + zero qkvec/qbk/zvb --------
__global__ __launch_bounds__(256) void k_setup(const float* __restrict__ x,
                                               unsigned short* __restrict__ xb,
                                               unsigned short* bufA,
                                               unsigned short* bufB,
                                               float* zbuf /* qkvec|qbk|zvb */) {
    const int NX = B_ * 64 * DIN_;
    const int NA = B_ * 64 * D_;
    const int NC = B_ * T_ * DIN_;
    const int NZ = 2 * B_ * D_ + 8;
    int i = blockIdx.x * 256 + threadIdx.x;
    if (i < NX) {
        const int b = i / (64 * DIN_), r = i - b * (64 * DIN_);
        xb[(size_t)b * PT_ * DIN_ + r] = 0;
        return;
    }
    i -= NX;
    if (i < NA) {
        const int b = i / (64 * D_), r = i - b * (64 * D_);
        bufA[(size_t)b * PT_ * D_ + r] = 0;
        return;
    }
    i -= NA;
    if (i < NA) {
        const int b = i / (64 * D_), r = i - b * (64 * D_);
        bufB[(size_t)b * PT_ * D_ + r] = 0;
        return;
    }
    i -= NA;
    if (i < NC) {
        const int b = i / (T_ * DIN_);
        const int r = i - b * (T_ * DIN_);
        xb[((size_t)b * PT_ + 64) * DIN_ + r] = f2bf(x[i]);
        return;
    }
    i -= NC;
    if (i < NZ) zbuf[i] = 0.0f;
}

// -------- fused weight convert+transpose for ALL 13 conv weight tensors --------
__global__ __launch_bounds__(256) void k_wcvt_all(const float* resw, const float* c1w0,
                                                  const float* c2w0, const float* c1w,
                                                  const float* c2w,
                                                  unsigned short* wRes, unsigned short* wC10,
                                                  unsigned short* wC20, unsigned short* wC1,
                                                  unsigned short* wC2) {
    const int l = blockIdx.y;
    const float* src;
    unsigned short* dst;
    int C_in, KS;
    if (l == 0)      { src = resw; dst = wRes; C_in = 64;  KS = 1; }
    else if (l == 1) { src = c1w0; dst = wC10; C_in = 64;  KS = 3; }
    else if (l == 2) { src = c2w0; dst = wC20; C_in = 512; KS = 3; }
    else if (l <= 7) { src = c1w + (size_t)(l - 3) * 512 * 512 * 3;
                       dst = wC1 + (size_t)(l - 3) * 3 * 512 * 512; C_in = 512; KS = 3; }
    else             { src = c2w + (size_t)(l - 8) * 512 * 512 * 3;
                       dst = wC2 + (size_t)(l - 8) * 3 * 512 * 512; C_in = 512; KS = 3; }
    const int n = 512 * C_in * KS;
    for (int i = blockIdx.x * 256 + threadIdx.x; i < n; i += gridDim.x * 256) {
        const int ci = i % C_in;
        const int r = i / C_in;
        const int co = r & 511;
        const int tap = r >> 9;
        dst[i] = f2bf(src[((size_t)co * C_in + ci) * KS + tap]);
    }
}

// -------- block-0 dual conv: y=0 -> 1x1 residual->bufA; y=1 -> 3-tap gelu->bufB --------
__global__ __launch_bounds__(256, 2) void k_conv_b0(const unsigned short* __restrict__ X,
                                                    const unsigned short* __restrict__ wRes,
                                                    const float* __restrict__ resb,
                                                    const unsigned short* __restrict__ wC10,
                                                    const float* __restrict__ c1b0,
                                                    unsigned short* bufA,
                                                    unsigned short* bufB) {
    const int tid = threadIdx.x;
    const int ib = blockIdx.x;
    const int work = (ib & 7) * 8 + (ib >> 3);
    const int co0 = (work & 3) * 128;
    const int t0 = (work >> 2) * 128;
    const int b = blockIdx.z;
    const int y = blockIdx.y;
    const int nks = y ? 3 : 1;
    const unsigned short* Wt = y ? wC10 : wRes;
    const float* bias = y ? c1b0 : resb;
    unsigned short* Y = y ? bufB : bufA;
    const int back = nks - 1;            // dil=1
    const int nx = (128 + back) * 8;

    __shared__ __align__(16) unsigned short sX[192 * 64];
    __shared__ __align__(16) unsigned short sW[3 * 128 * 64];

    const int lane = tid & 63;
    const int wv = tid >> 6;
    const int wco = (wv & 1) * 64;
    const int wt = (wv >> 1) * 64;
    const int tl = lane & 15;
    const int ch = lane >> 4;

    f32x4 acc[4][4] = {};

    const unsigned short* Xb = X + ((size_t)b * PT_ + 64) * DIN_;

#pragma unroll
    for (int k = 0; k < 6; ++k) {
        const int i = tid + k * 256;
        if (i < nx) {
            const int row = i >> 3, s = i & 7;
            int tg = t0 - back + row;
            if (tg >= T_) tg = T_ - 1;
            gload_lds16(Xb + (size_t)tg * DIN_ + ((s ^ (row & 7)) << 3), &sX[(i & ~63) * 8]);
        }
    }
    for (int k = 0; k < nks * 4; ++k) {
        const int i = tid + k * 256;
        const int row = i >> 3, s = i & 7;
        const int tap = row >> 7, rco = row & 127;
        gload_lds16(Wt + ((size_t)(tap * 512 + co0 + rco)) * DIN_ + ((s ^ (row & 7)) << 3),
                    &sW[(i & ~63) * 8]);
    }
    __syncthreads();

    for (int tap = 0; tap < nks; ++tap) {
        const int tapoff = tap;
#pragma unroll
        for (int kh = 0; kh < 2; ++kh) {
            const int j = kh * 4 + ch;
            bf16x8 a[4], bb[4];
#pragma unroll
            for (int m = 0; m < 4; ++m) {
                const int wr = tap * 128 + wco + m * 16 + tl;
                a[m] = *reinterpret_cast<const bf16x8*>(&sW[wr * 64 + ((j ^ (wr & 7)) << 3)]);
            }
#pragma unroll
            for (int n = 0; n < 4; ++n) {
                const int xr = wt + n * 16 + tl + tapoff;
                bb[n] = *reinterpret_cast<const bf16x8*>(&sX[xr * 64 + ((j ^ (xr & 7)) << 3)]);
            }
#pragma unroll
            for (int m = 0; m < 4; ++m)
#pragma unroll
                for (int n = 0; n < 4; ++n)
                    acc[m][n] = __builtin_amdgcn_mfma_f32_16x16x32_bf16(a[m], bb[n], acc[m][n], 0, 0, 0);
        }
    }

#pragma unroll
    for (int m = 0; m < 4; ++m) {
        const int co = co0 + wco + m * 16 + ch * 4;
        const float4 bv4 = *reinterpret_cast<const float4*>(&bias[co]);
#pragma unroll
        for (int n = 0; n < 4; ++n) {
            const int t = t0 + wt + n * 16 + tl;
            const size_t base = HROW(b, t) + co;
            float v[4];
            v[0] = acc[m][n][0] + bv4.x;
            v[1] = acc[m][n][1] + bv4.y;
            v[2] = acc[m][n][2] + bv4.z;
            v[3] = acc[m][n][3] + bv4.w;
            if (y) {
#pragma unroll
                for (int r = 0; r < 4; ++r) v[r] = gelu_f(v[r]);
            }
            uint2 o;
            o.x = (unsigned int)f2bf(v[0]) | ((unsigned int)f2bf(v[1]) << 16);
            o.y = (unsigned int)f2bf(v[2]) | ((unsigned int)f2bf(v[3]) << 16);
            *reinterpret_cast<uint2*>(&Y[base]) = o;
        }
    }
}

// -------- causal dilated conv via bf16 MFMA implicit GEMM (R11 structure) --------
// R17: CIN and DIL are template params -> constexpr NC/back/nx, static addressing,
// fully unrollable chunk loop (frees VALU issue slots; compiler can pre-schedule).
template <int KS, int MODE, int CIN, int DIL>
__global__ __launch_bounds__(256, 2) void k_conv_mfma(const unsigned short* __restrict__ X,
                                                      const unsigned short* __restrict__ Wt,
                                                      const float* __restrict__ bias,
                                                      const unsigned short* R,
                                                      unsigned short* Y) {
    constexpr int back = (KS - 1) * DIL;   // <= 64
    constexpr int XWIN = 128 + back;
    constexpr int nx = XWIN * 8;           // X 16B slots (<= 1536)
    constexpr int NC = CIN >> 6;

    const int tid = threadIdx.x;
    const int ib = blockIdx.x;
    const int work = (ib & 7) * 8 + (ib >> 3);   // [0,64)
    const int co0 = (work & 3) * 128;            // co fastest -> co-blocks co-located per XCD
    const int t0 = (work >> 2) * 128;
    const int b = blockIdx.z;

    __shared__ __align__(16) unsigned short sX[192 * 64];   // [row][ci64], swizzled slots
    __shared__ __align__(16) unsigned short sW[KS * 128 * 64];

    const int lane = tid & 63;
    const int wv = tid >> 6;
    const int wco = (wv & 1) * 64;
    const int wt = (wv >> 1) * 64;
    const int tl = lane & 15;
    const int ch = lane >> 4;

    f32x4 acc[4][4] = {};

    const unsigned short* Xb = X + ((size_t)b * PT_ + 64) * CIN;

    const unsigned short* xsrc[6];
#pragma unroll
    for (int k = 0; k < 6; ++k) {
        const int i = tid + k * 256;
        const int row = i >> 3, s = i & 7;
        int tg = t0 - back + row;                 // >= -64 (pad covers)
        if (tg >= T_) tg = T_ - 1;                // clamped rows are never read
        xsrc[k] = Xb + (size_t)tg * CIN + ((s ^ (row & 7)) << 3);
    }
    const unsigned short* wsrc[KS * 4];
#pragma unroll
    for (int k = 0; k < KS * 4; ++k) {
        const int i = tid + k * 256;
        const int row = i >> 3, s = i & 7;
        const int tap = row >> 7, rco = row & 127;
        wsrc[k] = Wt + ((size_t)(tap * 512 + co0 + rco)) * CIN + ((s ^ (row & 7)) << 3);
    }

    for (int c = 0; c < NC; ++c) {
        if (c) __syncthreads();  // protect buffer from waves still reading chunk c-1
#pragma unroll
        for (int k = 0; k < 6; ++k) {
            const int i = tid + k * 256;
            if (i < nx) gload_lds16(xsrc[k] + c * 64, &sX[(i & ~63) * 8]);
        }
#pragma unroll
        for (int k = 0; k < KS * 4; ++k) {
            const int i = tid + k * 256;
            gload_lds16(wsrc[k] + c * 64, &sW[(i & ~63) * 8]);
        }
        __syncthreads();  // drains vmcnt(0): tile ready

#pragma unroll
        for (int tap = 0; tap < KS; ++tap) {
            const int tapoff = tap * DIL;
#pragma unroll
            for (int ks = 0; ks < 2; ++ks) {
                const int j = ks * 4 + ch;
                bf16x8 a[4], bb[4];
#pragma unroll
                for (int m = 0; m < 4; ++m) {
                    const int wr = tap * 128 + wco + m * 16 + tl;
                    a[m] = *reinterpret_cast<const bf16x8*>(
                        &sW[wr * 64 + ((j ^ (wr & 7)) << 3)]);
                }
#pragma unroll
                for (int n = 0; n < 4; ++n) {
                    const int xr = wt + n * 16 + tl + tapoff;
                    bb[n] = *reinterpret_cast<const bf16x8*>(
                        &sX[xr * 64 + ((j ^ (xr & 7)) << 3)]);
                }
#pragma unroll
                for (int m = 0; m < 4; ++m)
#pragma unroll
                    for (int n = 0; n < 4; ++n)
                        acc[m][n] = __builtin_amdgcn_mfma_f32_16x16x32_bf16(a[m], bb[n], acc[m][n], 0, 0, 0);
            }
        }
    }

#pragma unroll
    for (int m = 0; m < 4; ++m) {
        const int co = co0 + wco + m * 16 + ch * 4;
        const float4 bv4 = *reinterpret_cast<const float4*>(&bias[co]);
#pragma unroll
        for (int n = 0; n < 4; ++n) {
            const int t = t0 + wt + n * 16 + tl;
            const size_t base = HROW(b, t) + co;
            float v[4];
            v[0] = acc[m][n][0] + bv4.x;
            v[1] = acc[m][n][1] + bv4.y;
            v[2] = acc[m][n][2] + bv4.z;
            v[3] = acc[m][n][3] + bv4.w;
            if (MODE >= 1) {
#pragma unroll
                for (int r = 0; r < 4; ++r) v[r] = gelu_f(v[r]);
            }
            if (MODE == 2) {
                const uint2 rr = *reinterpret_cast<const uint2*>(&R[base]);
                v[0] += bfu2f((unsigned short)(rr.x & 0xffffu));
                v[1] += bfu2f((unsigned short)(rr.x >> 16));
                v[2] += bfu2f((unsigned short)(rr.y & 0xffffu));
                v[3] += bfu2f((unsigned short)(rr.y >> 16));
            }
            uint2 o;
            o.x = (unsigned int)f2bf(v[0]) | ((unsigned int)f2bf(v[1]) << 16);
            o.y = (unsigned int)f2bf(v[2]) | ((unsigned int)f2bf(v[3]) << 16);
            *reinterpret_cast<uint2*>(&Y[base]) = o;
        }
    }
}

// -------- q[b][d] = bq[d] + wq[d,:] . z_last[b,:]; wave per d, all 8 b --------
__global__ __launch_bounds__(256) void k_q(const unsigned short* __restrict__ h,
                                           const float* __restrict__ wq,
                                           const float* __restrict__ bq,
                                           float* __restrict__ q) {
    __shared__ float zs[B_ * D_];
    const int tid = threadIdx.x;
    for (int i = tid; i < B_ * D_; i += 256) {
        const int b = i >> 9, c = i & 511;
        zs[i] = bfu2f(h[HROW(b, T_ - 1) + c]);
    }
    __syncthreads();
    const int wvi = tid >> 6, lane = tid & 63;
    const int d = blockIdx.x * 4 + wvi;
    const float* wr = wq + (size_t)d * D_ + lane * 8;
    float w8[8];
#pragma unroll
    for (int j = 0; j < 8; ++j) w8[j] = wr[j];
    float acc[B_];
#pragma unroll
    for (int b = 0; b < B_; ++b) {
        float a = 0.0f;
#pragma unroll
        for (int j = 0; j < 8; ++j) a += w8[j] * zs[b * D_ + lane * 8 + j];
        acc[b] = a;
    }
#pragma unroll
    for (int off = 32; off; off >>= 1) {
#pragma unroll
        for (int b = 0; b < B_; ++b) acc[b] += __shfl_xor(acc[b], off);
    }
    if (lane == 0) {
#pragma unroll
        for (int b = 0; b < B_; ++b) q[b * D_ + d] = acc[b] + bq[d];
    }
}

// -------- qkvec[b][c] += sum_{d in chunk} q[b][d]*wk[d][c]; + qbk partials --------
__global__ __launch_bounds__(512) void k_qk(const float* __restrict__ q,
                                            const float* __restrict__ wk,
                                            const float* __restrict__ bk,
                                            float* __restrict__ qkvec,
                                            float* __restrict__ qbk) {
    const int b = blockIdx.y, dc = blockIdx.x;
    const int tid = threadIdx.x;
    __shared__ float qs[64];
    if (tid < 64) qs[tid] = q[b * D_ + dc * 64 + tid];
    __syncthreads();
    float acc = 0.0f;
    const float* wbase = wk + (size_t)(dc * 64) * D_ + tid;
#pragma unroll 8
    for (int d = 0; d < 64; ++d) acc += qs[d] * wbase[(size_t)d * D_];
    atomicAdd(&qkvec[b * D_ + tid], acc);
    if (tid < 64) {
        float p = qs[tid] * bk[dc * 64 + tid];
#pragma unroll
        for (int off = 32; off; off >>= 1) p += __shfl_xor(p, off);
        if (tid == 0) atomicAdd(&qbk[b], p);
    }
}

// -------- scores[b,t] = (h[b,t,:] . qkvec[b,:] + qbk[b]) / sqrt(D), wave per t --------
__global__ __launch_bounds__(256) void k_scores(const unsigned short* __restrict__ h,
                                                const float* __restrict__ qkvec,
                                                const float* __restrict__ qbk,
                                                float* __restrict__ scores) {
    const int b = blockIdx.y;
    const int tid = threadIdx.x;
    __shared__ float qs[D_];
    qs[tid] = qkvec[b * D_ + tid];
    qs[tid + 256] = qkvec[b * D_ + tid + 256];
    __syncthreads();
    const int wvi = tid >> 6, lane = tid & 63;
    const int t = blockIdx.x * 4 + wvi;
    const uint4 v = *reinterpret_cast<const uint4*>(h + HROW(b, t) + lane * 8);
    const unsigned int w[4] = {v.x, v.y, v.z, v.w};
    float acc = 0.0f;
#pragma unroll
    for (int j = 0; j < 4; ++j) {
        acc += bfu2f((unsigned short)(w[j] & 0xffffu)) * qs[lane * 8 + 2 * j];
        acc += bfu2f((unsigned short)(w[j] >> 16)) * qs[lane * 8 + 2 * j + 1];
    }
    for (int off = 32; off; off >>= 1) acc += __shfl_down(acc, off);
    if (lane == 0) scores[b * T_ + t] = (acc + qbk[b]) * 0.04419417382415922f;
}

// -------- top-512 of 2048 via bitonic sort, then masked softmax weights --------
__global__ __launch_bounds__(1024) void k_topk(const float* __restrict__ scores,
                                               float* __restrict__ wts) {
    const int b = blockIdx.x;
    __shared__ float s[T_];
    __shared__ float v[T_];
    __shared__ float red[16];
    __shared__ float denom_s;
    for (int i = threadIdx.x; i < T_; i += 1024) {
        const float x = scores[b * T_ + i];
        s[i] = x; v[i] = x;
    }
    __syncthreads();
    for (unsigned kk = 2; kk <= T_; kk <<= 1) {
        for (unsigned j = kk >> 1; j > 0; j >>= 1) {
            for (unsigned i = threadIdx.x; i < T_; i += 1024) {
                const unsigned ixj = i ^ j;
                if (ixj > i) {
                    const float a = v[i], c2 = v[ixj];
                    const bool asc = ((i & kk) == 0);
                    if ((a > c2) == asc) { v[i] = c2; v[ixj] = a; }
                }
            }
            __syncthreads();
        }
    }
    const float thr = v[T_ - 512];
    const float mx = v[T_ - 1];
    float part = 0.0f;
    for (int i = threadIdx.x; i < T_; i += 1024) {
        const float x = s[i];
        if (x >= thr) part += expf(x - mx);
    }
    for (int off = 32; off; off >>= 1) part += __shfl_down(part, off);
    const int lane = threadIdx.x & 63, wv_ = threadIdx.x >> 6;
    if (lane == 0) red[wv_] = part;
    __syncthreads();
    if (threadIdx.x == 0) {
        float d = 0.0f;
        for (int i = 0; i < 16; ++i) d += red[i];
        denom_s = d;
    }
    __syncthreads();
    const float inv = 1.0f / denom_s;
    for (int i = threadIdx.x; i < T_; i += 1024) {
        const float x = s[i];
        wts[b * T_ + i] = (x >= thr) ? expf(x - mx) * inv : 0.0f;
    }
}

// -------- zv[b,c] = sum_t w[b,t]*h[b,t,c] (partial blocks + atomics) --------
__global__ __launch_bounds__(256) void k_zv(const unsigned short* __restrict__ h,
                                            const float* __restrict__ wts,
                                            float* __restrict__ zvb) {
    const int b = blockIdx.y;
    const int t0 = blockIdx.x * 256;
    const int tid = threadIdx.x;
    float a0 = 0.0f, a1 = 0.0f;
    for (int t = t0; t < t0 + 256; ++t) {
        const float w = wts[b * T_ + t];
        if (w != 0.0f) {
            const unsigned int v = *reinterpret_cast<const unsigned int*>(
                h + HROW(b, t) + tid * 2);
            a0 += w * bfu2f((unsigned short)(v & 0xffffu));
            a1 += w * bfu2f((unsigned short)(v >> 16));
        }
    }
    atomicAdd(&zvb[b * D_ + tid * 2], a0);
    atomicAdd(&zvb[b * D_ + tid * 2 + 1], a1);
}

// -------- u[b][e] = bv[e] + z_last[b][e] + wv[e,:] . zv[b,:]; wave per e --------
__global__ __launch_bounds__(256) void k_u(const unsigned short* __restrict__ h,
                                           const float* __restrict__ zvb,
                                           const float* __restrict__ wv,
                                           const float* __restrict__ bv,
                                           float* __restrict__ u) {
    __shared__ float zs[B_ * D_];
    const int tid = threadIdx.x;
    for (int i = tid; i < B_ * D_; i += 256) zs[i] = zvb[i];
    __syncthreads();
    const int wvi = tid >> 6, lane = tid & 63;
    const int e = blockIdx.x * 4 + wvi;
    const float* wr = wv + (size_t)e * D_ + lane * 8;
    float w8[8];
#pragma unroll
    for (int j = 0; j < 8; ++j) w8[j] = wr[j];
    float acc[B_];
#pragma unroll
    for (int b = 0; b < B_; ++b) {
        float a = 0.0f;
#pragma unroll
        for (int j = 0; j < 8; ++j) a += w8[j] * zs[b * D_ + lane * 8 + j];
        acc[b] = a;
    }
#pragma unroll
    for (int off = 32; off; off >>= 1) {
#pragma unroll
        for (int b = 0; b < B_; ++b) acc[b] += __shfl_xor(acc[b], off);
    }
    if (lane == 0) {
#pragma unroll
        for (int b = 0; b < B_; ++b)
            u[b * D_ + e] = acc[b] + bv[e] + bfu2f(h[HROW(b, T_ - 1) + e]);
    }
}

// -------- out[b][d] = bp[d] + wp[d,:] . u[b,:]; wave per d --------
__global__ __launch_bounds__(256) void k_out(const float* __restrict__ u,
                                             const float* __restrict__ wp,
                                             const float* __restrict__ bp,
                                             float* __restrict__ out) {
    __shared__ float us[B_ * D_];
    const int tid = threadIdx.x;
    for (int i = tid; i < B_ * D_; i += 256) us[i] = u[i];
    __syncthreads();
    const int wvi = tid >> 6, lane = tid & 63;
    const int d = blockIdx.x * 4 + wvi;
    const float* wr = wp + (size_t)d * D_ + lane * 8;
    float w8[8];
#pragma unroll
    for (int j = 0; j < 8; ++j) w8[j] = wr[j];
    float acc[B_];
#pragma unroll
    for (int b = 0; b < B_; ++b) {
        float a = 0.0f;
#pragma unroll
        for (int j = 0; j < 8; ++j) a += w8[j] * us[b * D_ + lane * 8 + j];
        acc[b] = a;
    }
#pragma unroll
    for (int off = 32; off; off >>= 1) {
#pragma unroll
        for (int b = 0; b < B_; ++b) acc[b] += __shfl_xor(acc[b], off);
    }
    if (lane == 0) {
#pragma unroll
        for (int b = 0; b < B_; ++b) out[b * D_ + d] = acc[b] + bp[d];
    }
}

extern "C" void kernel_launch(void* const* d_in, const int* in_sizes, int n_in,
                              void* d_out, int out_size, void* d_ws, size_t ws_size,
                              hipStream_t stream) {
    const float* x    = (const float*)d_in[0];
    const float* c1w0 = (const float*)d_in[1];
    const float* c1b0 = (const float*)d_in[2];
    const float* c2w0 = (const float*)d_in[3];
    const float* c2b0 = (const float*)d_in[4];
    const float* resw = (const float*)d_in[5];
    const float* resb = (const float*)d_in[6];
    const float* c1w  = (const float*)d_in[7];
    const float* c1b  = (const float*)d_in[8];
    const float* c2w  = (const float*)d_in[9];
    const float* c2b  = (const float*)d_in[10];
    const float* wq   = (const float*)d_in[11];
    const float* bq   = (const float*)d_in[12];
    const float* wk   = (const float*)d_in[13];
    const float* bk   = (const float*)d_in[14];
    const float* wvp  = (const float*)d_in[15];
    const float* bv   = (const float*)d_in[16];
    const float* wp   = (const float*)d_in[17];
    const float* bp   = (const float*)d_in[18];
    float* out = (float*)d_out;

    unsigned short* ws16 = (unsigned short*)d_ws;
    unsigned short* xb   = ws16;                           // B*PT*64
    unsigned short* bufA = xb + (size_t)B_ * PT_ * DIN_;   // B*PT*512
    unsigned short* bufB = bufA + (size_t)B_ * PT_ * D_;   // B*PT*512
    unsigned short* wRes = bufB + (size_t)B_ * PT_ * D_;   // 512*64
    unsigned short* wC10 = wRes + 512 * 64;                // 3*512*64
    unsigned short* wC20 = wC10 + 3 * 512 * 64;            // 3*512*512
    unsigned short* wC1  = wC20 + 3 * 512 * 512;           // 5*3*512*512
    unsigned short* wC2  = wC1 + (size_t)5 * 3 * 512 * 512;
    float* fws  = (float*)(wC2 + (size_t)5 * 3 * 512 * 512);
    float* qv    = fws;                 // 8*512 (no init)
    float* qkvec = qv + B_ * D_;        // 8*512 zero (k_setup)
    float* qbk   = qkvec + B_ * D_;     // 8     zero (k_setup)
    float* zvb   = qbk + 8;             // 8*512 zero (k_setup)
    float* uacc  = zvb + B_ * D_;       // 8*512 (no init)
    float* sc    = uacc + B_ * D_;      // 8*2048
    float* wts   = sc + B_ * T_;        // 8*2048

    const int nsetup = B_ * 64 * (DIN_ + 2 * D_) + B_ * T_ * DIN_ + 2 * B_ * D_ + 8;
    k_setup<<<dim3((nsetup + 255) / 256), 256, 0, stream>>>(x, xb, bufA, bufB, qkvec);
    k_wcvt_all<<<dim3(768, 13), 256, 0, stream>>>(resw, c1w0, c2w0, c1w, c2w,
                                                  wRes, wC10, wC20, wC1, wC2);

    const dim3 cgrid(64, 1, B_);
    // block 0: dual dispatch {residual 1x1 -> bufA || conv1 -> bufB}, then conv2+res -> bufA
    k_conv_b0<<<dim3(64, 2, B_), 256, 0, stream>>>(xb, wRes, resb, wC10, c1b0, bufA, bufB);
    k_conv_mfma<3, 2, 512, 1><<<cgrid, 256, 0, stream>>>(bufB, wC20, c2b0, bufA, bufA);
    // blocks 1..5 (dilations 2,4,8,16,32), identity residual (in place)
    {
        const size_t ws = (size_t)3 * 512 * 512;
        k_conv_mfma<3, 1, 512, 2><<<cgrid, 256, 0, stream>>>(bufA, wC1 + 0 * ws, c1b + 0 * D_, nullptr, bufB);
        k_conv_mfma<3, 2, 512, 2><<<cgrid, 256, 0, stream>>>(bufB, wC2 + 0 * ws, c2b + 0 * D_, bufA, bufA);
        k_conv_mfma<3, 1, 512, 4><<<cgrid, 256, 0, stream>>>(bufA, wC1 + 1 * ws, c1b + 1 * D_, nullptr, bufB);
        k_conv_mfma<3, 2, 512, 4><<<cgrid, 256, 0, stream>>>(bufB, wC2 + 1 * ws, c2b + 1 * D_, bufA, bufA);
        k_conv_mfma<3, 1, 512, 8><<<cgrid, 256, 0, stream>>>(bufA, wC1 + 2 * ws, c1b + 2 * D_, nullptr, bufB);
        k_conv_mfma<3, 2, 512, 8><<<cgrid, 256, 0, stream>>>(bufB, wC2 + 2 * ws, c2b + 2 * D_, bufA, bufA);
        k_conv_mfma<3, 1, 512, 16><<<cgrid, 256, 0, stream>>>(bufA, wC1 + 3 * ws, c1b + 3 * D_, nullptr, bufB);
        k_conv_mfma<3, 2, 512, 16><<<cgrid, 256, 0, stream>>>(bufB, wC2 + 3 * ws, c2b + 3 * D_, bufA, bufA);
        k_conv_mfma<3, 1, 512, 32><<<cgrid, 256, 0, stream>>>(bufA, wC1 + 4 * ws, c1b + 4 * D_, nullptr, bufB);
        k_conv_mfma<3, 2, 512, 32><<<cgrid, 256, 0, stream>>>(bufB, wC2 + 4 * ws, c2b + 4 * D_, bufA, bufA);
    }

    k_q<<<128, 256, 0, stream>>>(bufA, wq, bq, qv);
    k_qk<<<dim3(8, 8), 512, 0, stream>>>(qv, wk, bk, qkvec, qbk);
    k_scores<<<dim3(T_ / 4, B_), 256, 0, stream>>>(bufA, qkvec, qbk, sc);
    k_topk<<<B_, 1024, 0, stream>>>(sc, wts);
    k_zv<<<dim3(T_ / 256, B_), 256, 0, stream>>>(bufA, wts, zvb);
    k_u<<<128, 256, 0, stream>>>(bufA, zvb, wvp, bv, uacc);
    k_out<<<128, 256, 0, stream>>>(uacc, wp, bp, out);
}

// Round 18
// 447.867 us; speedup vs baseline: 1.3276x; 1.0114x over previous
//
#include <hip/hip_runtime.h>
#include <hip/hip_bf16.h>
#include <math.h>

#define B_ 8
#define T_ 2048
#define PT_ 2112   // T_ + 64 zero-pad rows at the start of each batch
#define DIN_ 64
#define D_ 512

typedef __attribute__((ext_vector_type(8))) short bf16x8;
typedef __attribute__((ext_vector_type(4))) float f32x4;

#define HROW(b, t) (((size_t)(b) * PT_ + 64 + (t)) * D_)

__device__ __forceinline__ float gelu_f(float x) {
    return 0.5f * x * (1.0f + erff(x * 0.70710678118654752440f));
}
__device__ __forceinline__ float bfu2f(unsigned short u) {
    union { float f; unsigned int i; } v; v.i = ((unsigned int)u) << 16; return v.f;
}
__device__ __forceinline__ unsigned short f2bf(float f) {
    unsigned int x = __float_as_uint(f);
    return (unsigned short)((x + 0x7FFFu + ((x >> 16) & 1u)) >> 16);
}
// async global->LDS, 16B per lane; lds dest is wave-uniform base (+ lane*16 by HW)
__device__ __forceinline__ void gload_lds16(const void* g, void* l) {
    __builtin_amdgcn_global_load_lds(
        (const __attribute__((address_space(1))) void*)g,
        (__attribute__((address_space(3))) void*)l, 16, 0, 0);
}

// -------- fused setup: zero pads + fp32->bf16 input + zero qkvec/qbk/zvb --------
__global__ __launch_bounds__(256) void k_setup(const float* __restrict__ x,
                                               unsigned short* __restrict__ xb,
                                               unsigned short* bufA,
                                               unsigned short* bufB,
                                               float* zbuf /* qkvec|qbk|zvb */) {
    const int NX = B_ * 64 * DIN_;
    const int NA = B_ * 64 * D_;
    const int NC = B_ * T_ * DIN_;
    const int NZ = 2 * B_ * D_ + 8;
    int i = blockIdx.x * 256 + threadIdx.x;
    if (i < NX) {
        const int b = i / (64 * DIN_), r = i - b * (64 * DIN_);
        xb[(size_t)b * PT_ * DIN_ + r] = 0;
        return;
    }
    i -= NX;
    if (i < NA) {
        const int b = i / (64 * D_), r = i - b * (64 * D_);
        bufA[(size_t)b * PT_ * D_ + r] = 0;
        return;
    }
    i -= NA;
    if (i < NA) {
        const int b = i / (64 * D_), r = i - b * (64 * D_);
        bufB[(size_t)b * PT_ * D_ + r] = 0;
        return;
    }
    i -= NA;
    if (i < NC) {
        const int b = i / (T_ * DIN_);
        const int r = i - b * (T_ * DIN_);
        xb[((size_t)b * PT_ + 64) * DIN_ + r] = f2bf(x[i]);
        return;
    }
    i -= NC;
    if (i < NZ) zbuf[i] = 0.0f;
}

// -------- fused weight convert+transpose for ALL 13 conv weight tensors --------
__global__ __launch_bounds__(256) void k_wcvt_all(const float* resw, const float* c1w0,
                                                  const float* c2w0, const float* c1w,
                                                  const float* c2w,
                                                  unsigned short* wRes, unsigned short* wC10,
                                                  unsigned short* wC20, unsigned short* wC1,
                                                  unsigned short* wC2) {
    const int l = blockIdx.y;
    const float* src;
    unsigned short* dst;
    int C_in, KS;
    if (l == 0)      { src = resw; dst = wRes; C_in = 64;  KS = 1; }
    else if (l == 1) { src = c1w0; dst = wC10; C_in = 64;  KS = 3; }
    else if (l == 2) { src = c2w0; dst = wC20; C_in = 512; KS = 3; }
    else if (l <= 7) { src = c1w + (size_t)(l - 3) * 512 * 512 * 3;
                       dst = wC1 + (size_t)(l - 3) * 3 * 512 * 512; C_in = 512; KS = 3; }
    else             { src = c2w + (size_t)(l - 8) * 512 * 512 * 3;
                       dst = wC2 + (size_t)(l - 8) * 3 * 512 * 512; C_in = 512; KS = 3; }
    const int n = 512 * C_in * KS;
    for (int i = blockIdx.x * 256 + threadIdx.x; i < n; i += gridDim.x * 256) {
        const int ci = i % C_in;
        const int r = i / C_in;
        const int co = r & 511;
        const int tap = r >> 9;
        dst[i] = f2bf(src[((size_t)co * C_in + ci) * KS + tap]);
    }
}

// -------- block-0 dual conv: y=0 -> 1x1 residual->bufA; y=1 -> 3-tap gelu->bufB --------
__global__ __launch_bounds__(256, 2) void k_conv_b0(const unsigned short* __restrict__ X,
                                                    const unsigned short* __restrict__ wRes,
                                                    const float* __restrict__ resb,
                                                    const unsigned short* __restrict__ wC10,
                                                    const float* __restrict__ c1b0,
                                                    unsigned short* bufA,
                                                    unsigned short* bufB) {
    const int tid = threadIdx.x;
    const int ib = blockIdx.x;
    const int work = (ib & 7) * 8 + (ib >> 3);
    const int co0 = (work & 3) * 128;
    const int t0 = (work >> 2) * 128;
    const int b = blockIdx.z;
    const int y = blockIdx.y;
    const int nks = y ? 3 : 1;
    const unsigned short* Wt = y ? wC10 : wRes;
    const float* bias = y ? c1b0 : resb;
    unsigned short* Y = y ? bufB : bufA;
    const int back = nks - 1;            // dil=1
    const int nx = (128 + back) * 8;

    __shared__ __align__(16) unsigned short sX[192 * 64];
    __shared__ __align__(16) unsigned short sW[3 * 128 * 64];

    const int lane = tid & 63;
    const int wv = tid >> 6;
    const int wco = (wv & 1) * 64;
    const int wt = (wv >> 1) * 64;
    const int tl = lane & 15;
    const int ch = lane >> 4;

    f32x4 acc[4][4] = {};

    const unsigned short* Xb = X + ((size_t)b * PT_ + 64) * DIN_;

#pragma unroll
    for (int k = 0; k < 6; ++k) {
        const int i = tid + k * 256;
        if (i < nx) {
            const int row = i >> 3, s = i & 7;
            int tg = t0 - back + row;
            if (tg >= T_) tg = T_ - 1;
            gload_lds16(Xb + (size_t)tg * DIN_ + ((s ^ (row & 7)) << 3), &sX[(i & ~63) * 8]);
        }
    }
    for (int k = 0; k < nks * 4; ++k) {
        const int i = tid + k * 256;
        const int row = i >> 3, s = i & 7;
        const int tap = row >> 7, rco = row & 127;
        gload_lds16(Wt + ((size_t)(tap * 512 + co0 + rco)) * DIN_ + ((s ^ (row & 7)) << 3),
                    &sW[(i & ~63) * 8]);
    }
    __syncthreads();

    for (int tap = 0; tap < nks; ++tap) {
        const int tapoff = tap;
#pragma unroll
        for (int kh = 0; kh < 2; ++kh) {
            const int j = kh * 4 + ch;
            bf16x8 a[4], bb[4];
#pragma unroll
            for (int m = 0; m < 4; ++m) {
                const int wr = tap * 128 + wco + m * 16 + tl;
                a[m] = *reinterpret_cast<const bf16x8*>(&sW[wr * 64 + ((j ^ (wr & 7)) << 3)]);
            }
#pragma unroll
            for (int n = 0; n < 4; ++n) {
                const int xr = wt + n * 16 + tl + tapoff;
                bb[n] = *reinterpret_cast<const bf16x8*>(&sX[xr * 64 + ((j ^ (xr & 7)) << 3)]);
            }
#pragma unroll
            for (int m = 0; m < 4; ++m)
#pragma unroll
                for (int n = 0; n < 4; ++n)
                    acc[m][n] = __builtin_amdgcn_mfma_f32_16x16x32_bf16(a[m], bb[n], acc[m][n], 0, 0, 0);
        }
    }

#pragma unroll
    for (int m = 0; m < 4; ++m) {
        const int co = co0 + wco + m * 16 + ch * 4;
        const float4 bv4 = *reinterpret_cast<const float4*>(&bias[co]);
#pragma unroll
        for (int n = 0; n < 4; ++n) {
            const int t = t0 + wt + n * 16 + tl;
            const size_t base = HROW(b, t) + co;
            float v[4];
            v[0] = acc[m][n][0] + bv4.x;
            v[1] = acc[m][n][1] + bv4.y;
            v[2] = acc[m][n][2] + bv4.z;
            v[3] = acc[m][n][3] + bv4.w;
            if (y) {
#pragma unroll
                for (int r = 0; r < 4; ++r) v[r] = gelu_f(v[r]);
            }
            uint2 o;
            o.x = (unsigned int)f2bf(v[0]) | ((unsigned int)f2bf(v[1]) << 16);
            o.y = (unsigned int)f2bf(v[2]) | ((unsigned int)f2bf(v[3]) << 16);
            *reinterpret_cast<uint2*>(&Y[base]) = o;
        }
    }
}

// -------- causal dilated conv via bf16 MFMA implicit GEMM --------
// R18: block tile 64co x 256t (4 waves, each 64co x 64t). Staged bytes/output
// -12.5% vs 128x128 (W 24.5KB + X 40KB = 64.5KB/chunk); X halo waste 50%->25%;
// all waves share W rows (broadcast reads). Grid 512 blocks, 2 blocks/CU,
// proven swizzle s^(row&7) + 2-barrier schedule + XCD remap (t-strip per XCD).
template <int KS, int MODE, int CIN, int DIL>
__global__ __launch_bounds__(256, 2) void k_conv_mfma(const unsigned short* __restrict__ X,
                                                      const unsigned short* __restrict__ Wt,
                                                      const float* __restrict__ bias,
                                                      const unsigned short* R,
                                                      unsigned short* Y) {
    constexpr int back = (KS - 1) * DIL;   // <= 64
    constexpr int nx = (256 + back) * 8;   // X 16B slots (<= 2560)
    constexpr int NC = CIN >> 6;

    const int tid = threadIdx.x;
    const int ib = blockIdx.x;
    const int work = (ib & 7) * 8 + (ib >> 3);   // [0,64)
    const int co0 = (work & 7) * 64;             // co fastest -> one t-strip x 8 co per XCD
    const int t0 = (work >> 3) * 256;
    const int b = blockIdx.z;

    __shared__ __align__(16) unsigned short sX[320 * 64];   // [row][ci64], swizzled slots
    __shared__ __align__(16) unsigned short sW[KS * 64 * 64];

    const int lane = tid & 63;
    const int wv = tid >> 6;
    const int wt = wv * 64;            // wave's t-offset (4 x 64 = 256)
    const int tl = lane & 15;
    const int ch = lane >> 4;

    f32x4 acc[4][4] = {};

    const unsigned short* Xb = X + ((size_t)b * PT_ + 64) * CIN;

    // X staging: up to 2560 slots / 256 thr -> 10 per thread (constexpr-guarded)
    const unsigned short* xsrc[10];
#pragma unroll
    for (int k = 0; k < 10; ++k) {
        const int i = tid + k * 256;
        const int row = i >> 3, s = i & 7;
        int tg = t0 - back + row;                 // >= -64 (pad covers)
        if (tg >= T_) tg = T_ - 1;                // clamped rows are never read
        xsrc[k] = Xb + (size_t)tg * CIN + ((s ^ (row & 7)) << 3);
    }
    // W staging: KS*64 rows x 8 slots = KS*512 slots / 256 thr -> KS*2 per thread
    const unsigned short* wsrc[KS * 2];
#pragma unroll
    for (int k = 0; k < KS * 2; ++k) {
        const int i = tid + k * 256;
        const int row = i >> 3, s = i & 7;
        const int tap = row >> 6, rco = row & 63;
        wsrc[k] = Wt + ((size_t)(tap * 512 + co0 + rco)) * CIN + ((s ^ (row & 7)) << 3);
    }

    for (int c = 0; c < NC; ++c) {
        if (c) __syncthreads();  // protect buffer from waves still reading chunk c-1
#pragma unroll
        for (int k = 0; k < 10; ++k) {
            const int i = tid + k * 256;
            if (i < nx) gload_lds16(xsrc[k] + c * 64, &sX[(i & ~63) * 8]);
        }
#pragma unroll
        for (int k = 0; k < KS * 2; ++k) {
            const int i = tid + k * 256;
            gload_lds16(wsrc[k] + c * 64, &sW[(i & ~63) * 8]);
        }
        __syncthreads();  // drains vmcnt(0): tile ready

#pragma unroll
        for (int tap = 0; tap < KS; ++tap) {
            const int tapoff = tap * DIL;
#pragma unroll
            for (int ks = 0; ks < 2; ++ks) {
                const int j = ks * 4 + ch;
                bf16x8 a[4], bb[4];
#pragma unroll
                for (int m = 0; m < 4; ++m) {
                    const int wr = tap * 64 + m * 16 + tl;
                    a[m] = *reinterpret_cast<const bf16x8*>(
                        &sW[wr * 64 + ((j ^ (wr & 7)) << 3)]);
                }
#pragma unroll
                for (int n = 0; n < 4; ++n) {
                    const int xr = wt + n * 16 + tl + tapoff;
                    bb[n] = *reinterpret_cast<const bf16x8*>(
                        &sX[xr * 64 + ((j ^ (xr & 7)) << 3)]);
                }
#pragma unroll
                for (int m = 0; m < 4; ++m)
#pragma unroll
                    for (int n = 0; n < 4; ++n)
                        acc[m][n] = __builtin_amdgcn_mfma_f32_16x16x32_bf16(a[m], bb[n], acc[m][n], 0, 0, 0);
            }
        }
    }

    // epilogue: lane frag(m,n): co = co0+m*16+ch*4+r, t = t0+wt+n*16+tl
#pragma unroll
    for (int m = 0; m < 4; ++m) {
        const int co = co0 + m * 16 + ch * 4;
        const float4 bv4 = *reinterpret_cast<const float4*>(&bias[co]);
#pragma unroll
        for (int n = 0; n < 4; ++n) {
            const int t = t0 + wt + n * 16 + tl;
            const size_t base = HROW(b, t) + co;
            float v[4];
            v[0] = acc[m][n][0] + bv4.x;
            v[1] = acc[m][n][1] + bv4.y;
            v[2] = acc[m][n][2] + bv4.z;
            v[3] = acc[m][n][3] + bv4.w;
            if (MODE >= 1) {
#pragma unroll
                for (int r = 0; r < 4; ++r) v[r] = gelu_f(v[r]);
            }
            if (MODE == 2) {
                const uint2 rr = *reinterpret_cast<const uint2*>(&R[base]);
                v[0] += bfu2f((unsigned short)(rr.x & 0xffffu));
                v[1] += bfu2f((unsigned short)(rr.x >> 16));
                v[2] += bfu2f((unsigned short)(rr.y & 0xffffu));
                v[3] += bfu2f((unsigned short)(rr.y >> 16));
            }
            uint2 o;
            o.x = (unsigned int)f2bf(v[0]) | ((unsigned int)f2bf(v[1]) << 16);
            o.y = (unsigned int)f2bf(v[2]) | ((unsigned int)f2bf(v[3]) << 16);
            *reinterpret_cast<uint2*>(&Y[base]) = o;
        }
    }
}

// -------- q[b][d] = bq[d] + wq[d,:] . z_last[b,:]; wave per d, all 8 b --------
__global__ __launch_bounds__(256) void k_q(const unsigned short* __restrict__ h,
                                           const float* __restrict__ wq,
                                           const float* __restrict__ bq,
                                           float* __restrict__ q) {
    __shared__ float zs[B_ * D_];
    const int tid = threadIdx.x;
    for (int i = tid; i < B_ * D_; i += 256) {
        const int b = i >> 9, c = i & 511;
        zs[i] = bfu2f(h[HROW(b, T_ - 1) + c]);
    }
    __syncthreads();
    const int wvi = tid >> 6, lane = tid & 63;
    const int d = blockIdx.x * 4 + wvi;
    const float* wr = wq + (size_t)d * D_ + lane * 8;
    float w8[8];
#pragma unroll
    for (int j = 0; j < 8; ++j) w8[j] = wr[j];
    float acc[B_];
#pragma unroll
    for (int b = 0; b < B_; ++b) {
        float a = 0.0f;
#pragma unroll
        for (int j = 0; j < 8; ++j) a += w8[j] * zs[b * D_ + lane * 8 + j];
        acc[b] = a;
    }
#pragma unroll
    for (int off = 32; off; off >>= 1) {
#pragma unroll
        for (int b = 0; b < B_; ++b) acc[b] += __shfl_xor(acc[b], off);
    }
    if (lane == 0) {
#pragma unroll
        for (int b = 0; b < B_; ++b) q[b * D_ + d] = acc[b] + bq[d];
    }
}

// -------- qkvec[b][c] += sum_{d in chunk} q[b][d]*wk[d][c]; + qbk partials --------
__global__ __launch_bounds__(512) void k_qk(const float* __restrict__ q,
                                            const float* __restrict__ wk,
                                            const float* __restrict__ bk,
                                            float* __restrict__ qkvec,
                                            float* __restrict__ qbk) {
    const int b = blockIdx.y, dc = blockIdx.x;
    const int tid = threadIdx.x;
    __shared__ float qs[64];
    if (tid < 64) qs[tid] = q[b * D_ + dc * 64 + tid];
    __syncthreads();
    float acc = 0.0f;
    const float* wbase = wk + (size_t)(dc * 64) * D_ + tid;
#pragma unroll 8
    for (int d = 0; d < 64; ++d) acc += qs[d] * wbase[(size_t)d * D_];
    atomicAdd(&qkvec[b * D_ + tid], acc);
    if (tid < 64) {
        float p = qs[tid] * bk[dc * 64 + tid];
#pragma unroll
        for (int off = 32; off; off >>= 1) p += __shfl_xor(p, off);
        if (tid == 0) atomicAdd(&qbk[b], p);
    }
}

// -------- scores[b,t] = (h[b,t,:] . qkvec[b,:] + qbk[b]) / sqrt(D), wave per t --------
__global__ __launch_bounds__(256) void k_scores(const unsigned short* __restrict__ h,
                                                const float* __restrict__ qkvec,
                                                const float* __restrict__ qbk,
                                                float* __restrict__ scores) {
    const int b = blockIdx.y;
    const int tid = threadIdx.x;
    __shared__ float qs[D_];
    qs[tid] = qkvec[b * D_ + tid];
    qs[tid + 256] = qkvec[b * D_ + tid + 256];
    __syncthreads();
    const int wvi = tid >> 6, lane = tid & 63;
    const int t = blockIdx.x * 4 + wvi;
    const uint4 v = *reinterpret_cast<const uint4*>(h + HROW(b, t) + lane * 8);
    const unsigned int w[4] = {v.x, v.y, v.z, v.w};
    float acc = 0.0f;
#pragma unroll
    for (int j = 0; j < 4; ++j) {
        acc += bfu2f((unsigned short)(w[j] & 0xffffu)) * qs[lane * 8 + 2 * j];
        acc += bfu2f((unsigned short)(w[j] >> 16)) * qs[lane * 8 + 2 * j + 1];
    }
    for (int off = 32; off; off >>= 1) acc += __shfl_down(acc, off);
    if (lane == 0) scores[b * T_ + t] = (acc + qbk[b]) * 0.04419417382415922f;
}

// -------- top-512 of 2048 via bitonic sort, then masked softmax weights --------
__global__ __launch_bounds__(1024) void k_topk(const float* __restrict__ scores,
                                               float* __restrict__ wts) {
    const int b = blockIdx.x;
    __shared__ float s[T_];
    __shared__ float v[T_];
    __shared__ float red[16];
    __shared__ float denom_s;
    for (int i = threadIdx.x; i < T_; i += 1024) {
        const float x = scores[b * T_ + i];
        s[i] = x; v[i] = x;
    }
    __syncthreads();
    for (unsigned kk = 2; kk <= T_; kk <<= 1) {
        for (unsigned j = kk >> 1; j > 0; j >>= 1) {
            for (unsigned i = threadIdx.x; i < T_; i += 1024) {
                const unsigned ixj = i ^ j;
                if (ixj > i) {
                    const float a = v[i], c2 = v[ixj];
                    const bool asc = ((i & kk) == 0);
                    if ((a > c2) == asc) { v[i] = c2; v[ixj] = a; }
                }
            }
            __syncthreads();
        }
    }
    const float thr = v[T_ - 512];
    const float mx = v[T_ - 1];
    float part = 0.0f;
    for (int i = threadIdx.x; i < T_; i += 1024) {
        const float x = s[i];
        if (x >= thr) part += expf(x - mx);
    }
    for (int off = 32; off; off >>= 1) part += __shfl_down(part, off);
    const int lane = threadIdx.x & 63, wv_ = threadIdx.x >> 6;
    if (lane == 0) red[wv_] = part;
    __syncthreads();
    if (threadIdx.x == 0) {
        float d = 0.0f;
        for (int i = 0; i < 16; ++i) d += red[i];
        denom_s = d;
    }
    __syncthreads();
    const float inv = 1.0f / denom_s;
    for (int i = threadIdx.x; i < T_; i += 1024) {
        const float x = s[i];
        wts[b * T_ + i] = (x >= thr) ? expf(x - mx) * inv : 0.0f;
    }
}

// -------- zv[b,c] = sum_t w[b,t]*h[b,t,c] (partial blocks + atomics) --------
__global__ __launch_bounds__(256) void k_zv(const unsigned short* __restrict__ h,
                                            const float* __restrict__ wts,
                                            float* __restrict__ zvb) {
    const int b = blockIdx.y;
    const int t0 = blockIdx.x * 256;
    const int tid = threadIdx.x;
    float a0 = 0.0f, a1 = 0.0f;
    for (int t = t0; t < t0 + 256; ++t) {
        const float w = wts[b * T_ + t];
        if (w != 0.0f) {
            const unsigned int v = *reinterpret_cast<const unsigned int*>(
                h + HROW(b, t) + tid * 2);
            a0 += w * bfu2f((unsigned short)(v & 0xffffu));
            a1 += w * bfu2f((unsigned short)(v >> 16));
        }
    }
    atomicAdd(&zvb[b * D_ + tid * 2], a0);
    atomicAdd(&zvb[b * D_ + tid * 2 + 1], a1);
}

// -------- u[b][e] = bv[e] + z_last[b][e] + wv[e,:] . zv[b,:]; wave per e --------
__global__ __launch_bounds__(256) void k_u(const unsigned short* __restrict__ h,
                                           const float* __restrict__ zvb,
                                           const float* __restrict__ wv,
                                           const float* __restrict__ bv,
                                           float* __restrict__ u) {
    __shared__ float zs[B_ * D_];
    const int tid = threadIdx.x;
    for (int i = tid; i < B_ * D_; i += 256) zs[i] = zvb[i];
    __syncthreads();
    const int wvi = tid >> 6, lane = tid & 63;
    const int e = blockIdx.x * 4 + wvi;
    const float* wr = wv + (size_t)e * D_ + lane * 8;
    float w8[8];
#pragma unroll
    for (int j = 0; j < 8; ++j) w8[j] = wr[j];
    float acc[B_];
#pragma unroll
    for (int b = 0; b < B_; ++b) {
        float a = 0.0f;
#pragma unroll
        for (int j = 0; j < 8; ++j) a += w8[j] * zs[b * D_ + lane * 8 + j];
        acc[b] = a;
    }
#pragma unroll
    for (int off = 32; off; off >>= 1) {
#pragma unroll
        for (int b = 0; b < B_; ++b) acc[b] += __shfl_xor(acc[b], off);
    }
    if (lane == 0) {
#pragma unroll
        for (int b = 0; b < B_; ++b)
            u[b * D_ + e] = acc[b] + bv[e] + bfu2f(h[HROW(b, T_ - 1) + e]);
    }
}

// -------- out[b][d] = bp[d] + wp[d,:] . u[b,:]; wave per d --------
__global__ __launch_bounds__(256) void k_out(const float* __restrict__ u,
                                             const float* __restrict__ wp,
                                             const float* __restrict__ bp,
                                             float* __restrict__ out) {
    __shared__ float us[B_ * D_];
    const int tid = threadIdx.x;
    for (int i = tid; i < B_ * D_; i += 256) us[i] = u[i];
    __syncthreads();
    const int wvi = tid >> 6, lane = tid & 63;
    const int d = blockIdx.x * 4 + wvi;
    const float* wr = wp + (size_t)d * D_ + lane * 8;
    float w8[8];
#pragma unroll
    for (int j = 0; j < 8; ++j) w8[j] = wr[j];
    float acc[B_];
#pragma unroll
    for (int b = 0; b < B_; ++b) {
        float a = 0.0f;
#pragma unroll
        for (int j = 0; j < 8; ++j) a += w8[j] * us[b * D_ + lane * 8 + j];
        acc[b] = a;
    }
#pragma unroll
    for (int off = 32; off; off >>= 1) {
#pragma unroll
        for (int b = 0; b < B_; ++b) acc[b] += __shfl_xor(acc[b], off);
    }
    if (lane == 0) {
#pragma unroll
        for (int b = 0; b < B_; ++b) out[b * D_ + d] = acc[b] + bp[d];
    }
}

extern "C" void kernel_launch(void* const* d_in, const int* in_sizes, int n_in,
                              void* d_out, int out_size, void* d_ws, size_t ws_size,
                              hipStream_t stream) {
    const float* x    = (const float*)d_in[0];
    const float* c1w0 = (const float*)d_in[1];
    const float* c1b0 = (const float*)d_in[2];
    const float* c2w0 = (const float*)d_in[3];
    const float* c2b0 = (const float*)d_in[4];
    const float* resw = (const float*)d_in[5];
    const float* resb = (const float*)d_in[6];
    const float* c1w  = (const float*)d_in[7];
    const float* c1b  = (const float*)d_in[8];
    const float* c2w  = (const float*)d_in[9];
    const float* c2b  = (const float*)d_in[10];
    const float* wq   = (const float*)d_in[11];
    const float* bq   = (const float*)d_in[12];
    const float* wk   = (const float*)d_in[13];
    const float* bk   = (const float*)d_in[14];
    const float* wvp  = (const float*)d_in[15];
    const float* bv   = (const float*)d_in[16];
    const float* wp   = (const float*)d_in[17];
    const float* bp   = (const float*)d_in[18];
    float* out = (float*)d_out;

    unsigned short* ws16 = (unsigned short*)d_ws;
    unsigned short* xb   = ws16;                           // B*PT*64
    unsigned short* bufA = xb + (size_t)B_ * PT_ * DIN_;   // B*PT*512
    unsigned short* bufB = bufA + (size_t)B_ * PT_ * D_;   // B*PT*512
    unsigned short* wRes = bufB + (size_t)B_ * PT_ * D_;   // 512*64
    unsigned short* wC10 = wRes + 512 * 64;                // 3*512*64
    unsigned short* wC20 = wC10 + 3 * 512 * 64;            // 3*512*512
    unsigned short* wC1  = wC20 + 3 * 512 * 512;           // 5*3*512*512
    unsigned short* wC2  = wC1 + (size_t)5 * 3 * 512 * 512;
    float* fws  = (float*)(wC2 + (size_t)5 * 3 * 512 * 512);
    float* qv    = fws;                 // 8*512 (no init)
    float* qkvec = qv + B_ * D_;        // 8*512 zero (k_setup)
    float* qbk   = qkvec + B_ * D_;     // 8     zero (k_setup)
    float* zvb   = qbk + 8;             // 8*512 zero (k_setup)
    float* uacc  = zvb + B_ * D_;       // 8*512 (no init)
    float* sc    = uacc + B_ * D_;      // 8*2048
    float* wts   = sc + B_ * T_;        // 8*2048

    const int nsetup = B_ * 64 * (DIN_ + 2 * D_) + B_ * T_ * DIN_ + 2 * B_ * D_ + 8;
    k_setup<<<dim3((nsetup + 255) / 256), 256, 0, stream>>>(x, xb, bufA, bufB, qkvec);
    k_wcvt_all<<<dim3(768, 13), 256, 0, stream>>>(resw, c1w0, c2w0, c1w, c2w,
                                                  wRes, wC10, wC20, wC1, wC2);

    const dim3 cgrid(64, 1, B_);
    // block 0: dual dispatch {residual 1x1 -> bufA || conv1 -> bufB}, then conv2+res -> bufA
    k_conv_b0<<<dim3(64, 2, B_), 256, 0, stream>>>(xb, wRes, resb, wC10, c1b0, bufA, bufB);
    k_conv_mfma<3, 2, 512, 1><<<cgrid, 256, 0, stream>>>(bufB, wC20, c2b0, bufA, bufA);
    // blocks 1..5 (dilations 2,4,8,16,32), identity residual (in place)
    {
        const size_t ws = (size_t)3 * 512 * 512;
        k_conv_mfma<3, 1, 512, 2><<<cgrid, 256, 0, stream>>>(bufA, wC1 + 0 * ws, c1b + 0 * D_, nullptr, bufB);
        k_conv_mfma<3, 2, 512, 2><<<cgrid, 256, 0, stream>>>(bufB, wC2 + 0 * ws, c2b + 0 * D_, bufA, bufA);
        k_conv_mfma<3, 1, 512, 4><<<cgrid, 256, 0, stream>>>(bufA, wC1 + 1 * ws, c1b + 1 * D_, nullptr, bufB);
        k_conv_mfma<3, 2, 512, 4><<<cgrid, 256, 0, stream>>>(bufB, wC2 + 1 * ws, c2b + 1 * D_, bufA, bufA);
        k_conv_mfma<3, 1, 512, 8><<<cgrid, 256, 0, stream>>>(bufA, wC1 + 2 * ws, c1b + 2 * D_, nullptr, bufB);
        k_conv_mfma<3, 2, 512, 8><<<cgrid, 256, 0, stream>>>(bufB, wC2 + 2 * ws, c2b + 2 * D_, bufA, bufA);
        k_conv_mfma<3, 1, 512, 16><<<cgrid, 256, 0, stream>>>(bufA, wC1 + 3 * ws, c1b + 3 * D_, nullptr, bufB);
        k_conv_mfma<3, 2, 512, 16><<<cgrid, 256, 0, stream>>>(bufB, wC2 + 3 * ws, c2b + 3 * D_, bufA, bufA);
        k_conv_mfma<3, 1, 512, 32><<<cgrid, 256, 0, stream>>>(bufA, wC1 + 4 * ws, c1b + 4 * D_, nullptr, bufB);
        k_conv_mfma<3, 2, 512, 32><<<cgrid, 256, 0, stream>>>(bufB, wC2 + 4 * ws, c2b + 4 * D_, bufA, bufA);
    }

    k_q<<<128, 256, 0, stream>>>(bufA, wq, bq, qv);
    k_qk<<<dim3(8, 8), 512, 0, stream>>>(qv, wk, bk, qkvec, qbk);
    k_scores<<<dim3(T_ / 4, B_), 256, 0, stream>>>(bufA, qkvec, qbk, sc);
    k_topk<<<B_, 1024, 0, stream>>>(sc, wts);
    k_zv<<<dim3(T_ / 256, B_), 256, 0, stream>>>(bufA, wts, zvb);
    k_u<<<128, 256, 0, stream>>>(bufA, zvb, wvp, bv, uacc);
    k_out<<<128, 256, 0, stream>>>(uacc, wp, bp, out);
}